// Round 11
// baseline (980.928 us; speedup 1.0000x reference)
//
#include <hip/hip_runtime.h>
#include <hip/hip_bf16.h>
#include <stdint.h>

// Problem constants
#define N_NODES 50000
#define SEQ_L   32
#define NE_BIG  800000
#define NE_SUB  200000
#define DSTRIDE 64          // padded-CSR slots per node (Poisson(16) in-degree; P(>64) ~ 2e-18)
#define BNREP   64          // bnsums replication factor (kills the 800K-atomics-to-16-lines funnel)

typedef __hip_bfloat16 bf16;
typedef unsigned short u16;
typedef unsigned int u32;
typedef _Float16 f16;
typedef _Float16 v8h __attribute__((ext_vector_type(8)));  // 8 f16 in 4 VGPRs (MFMA A/B frag)
typedef float v4f __attribute__((ext_vector_type(4)));     // MFMA C/D frag

// fast exp2 -> single v_exp_f32 (weights are pre-scaled by log2e so gates are in exp2 domain)
#if __has_builtin(__builtin_amdgcn_exp2f)
#define EXP2(x) __builtin_amdgcn_exp2f(x)
#else
extern "C" __device__ float __ocml_native_exp2_f32(float);
#define EXP2(x) __ocml_native_exp2_f32(x)
#endif
#define LOG2E  1.4426950408889634f
#define LOG2E2 2.8853900817779268f
#define GCLAMP 43.280851226668902f   // 15 * 2*log2e

#define MFMA16(a, b, c) __builtin_amdgcn_mfma_f32_16x16x32_f16(a, b, c, 0, 0, 0)

__device__ __forceinline__ float b2f(bf16 x) { return __bfloat162float(x); }
__device__ __forceinline__ float leakyf(float v) { return v >= 0.f ? v : 0.01f * v; }
__device__ __forceinline__ u16 f2h_bits(float x) { f16 h = (f16)x; u16 b; __builtin_memcpy(&b, &h, 2); return b; }
__device__ __forceinline__ float h2f(u16 b) { f16 h; __builtin_memcpy(&h, &b, 2); return (float)h; }
__device__ __forceinline__ uint pack2h(float a, float b) { return (uint)f2h_bits(a) | ((uint)f2h_bits(b) << 16); }

// load float input element i, dtype per flag (1 = bf16 storage, 0 = fp32 storage)
__device__ __forceinline__ float ldf(const void* p, int i, int isbf) {
  return isbf ? b2f(((const bf16*)p)[i]) : ((const float*)p)[i];
}

// Per-block dtype self-detection: sample 256 even-index uint16s of emb_url.
__device__ __forceinline__ int detect_isbf(const u16* __restrict__ u) {
  __shared__ int insane;
  if (threadIdx.x == 0) insane = 0;
  __syncthreads();
  int expo = (u[threadIdx.x * 2] >> 7) & 0xFF;
  if (expo >= 147) atomicAdd(&insane, 1);
  __syncthreads();
  return insane == 0;
}

// ---------------- binned graph build constants ----------------
// r11: phase-1 chunk 8192 -> 2048. The old 196-block grid left 60 CUs idle and 1 block/CU
// elsewhere (12.5% occupancy) on a latency-chained 5-pass pipeline -> phase-1 was the hidden
// ~200us #2 cost. 782 blocks (~3/CU, 12 waves/CU) hide the atomic/load latencies; LDS drops
// 38.7 -> 14.6KB. Cost: shorter bucket runs (~5 edges) add ~20MB of partial-line writes.
#define NBUCK   391                 // ceil(50000/128) buckets of 128 nodes
#define BSHIFT  7
#define BCAP    3072                // per-bucket capacity; mean 2048, sd~45 -> +22 sigma
#define P1_EPT   8
#define P1_CHUNK (256 * P1_EPT)     // 2048 edges per block
#define P1_NCH   ((NE_BIG + P1_CHUNK - 1) / P1_CHUNK)   // 391
#define P1_BLOCKS (P1_NCH * 2)      // x2 relations = 782
#define LSTM_XB  782                // LSTM blocks per dir
#define LSTM_EXTRA 587              // ceil((2*NBUCK + 391)/2): phase2 + rsq blocks per y-plane

// ---------------- PREP + PHASE-1 EDGE BINNING ----------------
// Zeroing of cnt4/cnt33/cur33/gcur/bnsums happens via ONE hipMemsetAsync before this kernel.
struct PrepArgs {
  const void* Whh_f; const void* Whh_b; const void* fc_W; const void* cls_W1;
  const void* g0sW; const void* g0uW; const void* g1sW; const void* g1uW;
  const void* emb_cat; const void* emb_country; const void* emb_sl;
  const void* fc_b; const void* cls_b1; const void* g0sb; const void* g0ub;
  const void* g1sb; const void* g1ub; const void* bn_g; const void* bn_b;
  const void* cls_W2; const void* cls_b2;
  const void* emb_url; const void* Wih_f; const void* b_f; const void* Wih_b; const void* b_b;
  f16* Whh_h; u16* Bfc; u16* BW1; u16* Bg0; u16* Bg1;
  u16* embc_h; u16* embco_h; u16* embs_h;
  float* fcb; float* b1; float* g0sbP; float* g0ubP; float* g1sbP; float* g1ubP;
  float* bngP; float* bnbP; float* W2P; float* b2P;
  int* dflag;
  float* Xperm;
  // graph part
  const int* sm; int* lens; int* cnt33;
  const int* s0; const int* d0; const int* s1; const int* d1;
  int* cnt4; int* gcur; u32* bucket;
};

__global__ __launch_bounds__(256) void prep_graph_kernel(PrepArgs A) {
  const int bid = blockIdx.x;
  const int t = threadIdx.x;

  // LDS for phase-1 binning (14.6KB -> up to 8 blocks/CU)
  __shared__ u32 stage[P1_CHUNK];          // 8 KB, bucket-ordered packed records
  __shared__ int hcnt[NBUCK];
  __shared__ int hstart[NBUCK];
  __shared__ int gbase[NBUCK];
  __shared__ int scanbuf[512];

  if (bid < P1_BLOCKS) {   // ---- phase-1: bin edges by dst>>7 ----
    const int rel = bid & 1;
    const int chunk = bid >> 1;
    const int* s = rel ? A.s1 : A.s0;
    const int* d = rel ? A.d1 : A.d0;
    int* outdeg = A.cnt4 + (size_t)rel * 2 * N_NODES;
    int* gcur = A.gcur + rel * NBUCK;
    u32* bbuf = A.bucket + (size_t)rel * NBUCK * BCAP;
    const int e0 = chunk * P1_CHUNK;
    const int cn = min(NE_BIG - e0, P1_CHUNK);

    for (int b = t; b < NBUCK; b += 256) hcnt[b] = 0;
    __syncthreads();
    // pass A: out-degree atomics (no-return) + local histogram
#pragma unroll
    for (int k = 0; k < P1_EPT; ++k) {
      int i = t + k * 256;
      if (i < cn) {
        int sv = s[e0 + i], dv = d[e0 + i];
        atomicAdd(&outdeg[sv], 1);
        atomicAdd(&hcnt[dv >> BSHIFT], 1);
      }
    }
    __syncthreads();
    // pass B: inclusive Hillis-Steele scan over 512 (2 elems/thread)
    scanbuf[t] = (t < NBUCK) ? hcnt[t] : 0;
    scanbuf[t + 256] = (t + 256 < NBUCK) ? hcnt[t + 256] : 0;
    __syncthreads();
    for (int off = 1; off < 512; off <<= 1) {
      int a0 = (t >= off) ? scanbuf[t - off] : 0;
      int a1 = (t + 256 >= off) ? scanbuf[t + 256 - off] : 0;
      __syncthreads();
      scanbuf[t] += a0;
      scanbuf[t + 256] += a1;
      __syncthreads();
    }
    // reserve global ranges (1 atomic per non-empty bucket), reset live cursors
    for (int b = t; b < NBUCK; b += 256) {
      int c = hcnt[b];
      int st = scanbuf[b] - c;       // exclusive prefix
      hstart[b] = st;
      gbase[b] = (c > 0) ? atomicAdd(&gcur[b], c) : 0;
      scanbuf[b] = st;               // live cursor for pass C
    }
    __syncthreads();
    // pass C: re-read edges (L2-hot), place bucket-ordered into stage
#pragma unroll
    for (int k = 0; k < P1_EPT; ++k) {
      int i = t + k * 256;
      if (i < cn) {
        int sv = s[e0 + i], dv = d[e0 + i];
        int b = dv >> BSHIFT;
        int pos = atomicAdd(&scanbuf[b], 1);
        stage[pos] = ((u32)b << 23) | ((u32)sv << 7) | (u32)(dv & 127);
      }
    }
    __syncthreads();
    // pass D: contiguous per-bucket runs out to global bucket segments
    for (int i = t; i < cn; i += 256) {
      u32 r = stage[i];
      int b = r >> 23;
      int o = gbase[b] + (i - hstart[b]);
      if (o < BCAP) bbuf[(size_t)b * BCAP + o] = r;
    }
    return;
  }

  const int b = bid - P1_BLOCKS;

  if (b >= 990) {    // ---- seq lens: 196 blocks ----
    int i = (b - 990) * 256 + t;
    if (i >= N_NODES) return;
    int len = 0;
#pragma unroll
    for (int tt = 0; tt < SEQ_L; ++tt) len += __builtin_nontemporal_load(A.sm + i * SEQ_L + tt);
    A.lens[i] = len;
    atomicAdd(&A.cnt33[len], 1);
    return;
  }

  const int isbf = detect_isbf((const u16*)A.emb_url);
  auto cpy = [&](const void* s, float* d, int n, int boff) {
    int i = (b - boff) * 256 + t;
    if (i < n) d[i] = ldf(s, i, isbf);
  };
  auto cvh = [&](const void* s, u16* d, int n, int boff) {
    int i = (b - boff) * 256 + t;
    if (i < n) d[i] = f2h_bits(ldf(s, i, isbf));
  };
  // Whh convert with log2e prescale (gate g=rows[128,192) gets 2*log2e): exp2-domain gates
  auto cvhW = [&](const void* s, u16* d, int boff) {
    int i = (b - boff) * 256 + t;     // i in [0,16384)
    float sc = ((i >> 12) == 2) ? LOG2E2 : LOG2E;   // i>>6 = row, row>>6 = gate
    d[i] = f2h_bits(ldf(s, i, isbf) * sc);
  };
  auto trh = [&](const void* s, u16* d, int R, int C, int KOFF, int boff) {  // d[c*256+KOFF+r]
    int i = (b - boff) * 256 + t;
    if (i < R * C) { int r = i / C, c = i % C; d[c * 256 + KOFF + r] = f2h_bits(ldf(s, i, isbf)); }
  };
  if      (b <   64) cvhW(A.Whh_f, (u16*)A.Whh_h, 0);
  else if (b <  128) cvhW(A.Whh_b, (u16*)(A.Whh_h + 16384), 64);
  else if (b <  160) cvh(A.fc_W, A.Bfc, 8192, 128);
  else if (b <  288) {
    // cls_W1 (128x256) -> Bcat [256 cols][K=128]: col j = W1[j][0:128] (G1 half),
    // col 128+j = W1[j][128:256] (G2 half). Enables the gather-free classifier
    // z[e] = G1[src] + G2[dst] + b1.
    int i = (b - 160) * 256 + t;     // i < 32768
    int j = i >> 8, k = i & 255;
    A.BW1[(size_t)(((k >> 7) * 128 + j) * 128 + (k & 127))] = f2h_bits(ldf(A.cls_W1, i, isbf));
  }
  else if (b <  416) trh(A.g0sW, A.Bg0, 256, 128, 0, 288);
  else if (b <  544) trh(A.g0uW, A.Bg0 + 128 * 256, 256, 128, 0, 416);
  else if (b <  608) trh(A.g1sW, A.Bg1, 128, 128, 0, 544);
  else if (b <  672) trh(A.g1uW, A.Bg1, 128, 128, 128, 608);
  else if (b <  698) cvh(A.emb_cat, A.embc_h, 6464, 672);
  else if (b <  721) cvh(A.emb_country, A.embco_h, 5888, 698);
  else if (b <  723) cvh(A.emb_sl, A.embs_h, 384, 721);
  else if (b <  724) cpy(A.fc_b, A.fcb, 64, 723);
  else if (b <  725) cpy(A.cls_b1, A.b1, 128, 724);
  else if (b <  726) cpy(A.g0sb, A.g0sbP, 128, 725);
  else if (b <  727) cpy(A.g0ub, A.g0ubP, 128, 726);
  else if (b <  728) cpy(A.g1sb, A.g1sbP, 128, 727);
  else if (b <  729) cpy(A.g1ub, A.g1ubP, 128, 728);
  else if (b <  730) cpy(A.bn_g, A.bngP, 128, 729);
  else if (b <  731) cpy(A.bn_b, A.bnbP, 128, 730);
  else if (b <  732) cpy(A.cls_W2, A.W2P, 256, 731);
  else if (b <  733) { cpy(A.cls_b2, A.b2P, 2, 732); if (t == 0) A.dflag[0] = isbf; }
  else if (b <  989) {                                   // xproj: 256 blocks
    int bb = b - 733;
    int dir = bb >> 7;
    int v = bb & 127;
    const void* Wih = dir ? A.Wih_b : A.Wih_f;
    const void* bias = dir ? A.b_b : A.b_f;
    __shared__ float embL[64];
    if (t < 64) embL[t] = ldf(A.emb_url, v * 64 + t, isbf);
    __syncthreads();
    float acc = ldf(bias, t, isbf);
#pragma unroll 8
    for (int j = 0; j < 64; ++j) acc += embL[j] * ldf(Wih, t * 64 + j, isbf);
    int g = t >> 6, unit = t & 63;
    float sc = (g == 2) ? LOG2E2 : LOG2E;                // exp2-domain prescale (matches Whh)
    A.Xperm[(size_t)dir * 128 * 256 + v * 256 + unit * 4 + g] = acc * sc;
  }
}
#define PG_BLOCKS (P1_BLOCKS + 1186)

// ---------------- permfill (self-prefix over 33 buckets, descending) ----------------
__global__ __launch_bounds__(256) void permfill_kernel(
    const int* __restrict__ lens, const int* __restrict__ cnt33, int* __restrict__ cur33,
    int* __restrict__ perm)
{
  int i = blockIdx.x * 256 + threadIdx.x;
  if (i >= N_NODES) return;
  int len = lens[i];
  int base = 0;
  for (int l = len + 1; l <= SEQ_L; ++l) base += cnt33[l];   // longest-first
  int p = atomicAdd(&cur33[len], 1);
  perm[base + p] = i;
}
#define PF_BLOCKS 196

// ---------------- MFMA LSTM + merged PHASE-2 scatter / rsq fills --------------------------
__global__ __launch_bounds__(256, 4) void lstm_mfma_kernel(
    const int* __restrict__ perm, const int* __restrict__ lens,
    const int* __restrict__ toksg,         // [N][32]
    const float* __restrict__ Xperm,       // [2][128][64][4]  (bias folded, gate-permuted, exp2-scaled)
    const f16* __restrict__ Whh_h,         // [2][256][64] fp16 (exp2-scaled)
    u16* __restrict__ hcat_h,              // [N][128] fp16 bits
    const u32* __restrict__ bucket, const int* __restrict__ gcur,
    u16* __restrict__ col0, u16* __restrict__ col1,
    int* __restrict__ cnt4, float* __restrict__ rsq4,
    int nnodes)
{
  // H rows: 64 data f16 + 8 pad f16 (bank skew). The 128 rows x 16 pad bytes = 2048B host
  // the token table: entry i = step*64+node lives at byte (i>>4)*144 + 128 + (i&15).
  __shared__ __align__(16) f16 H[2][64 * 72];   // 18.4 KB total (incl. token pad)
  __shared__ int permL[64];
  __shared__ int lensL[64];
  __shared__ int cutL[SEQ_L + 1];
  const int tid = threadIdx.x;
  const int bx = blockIdx.x;
  const int dir = blockIdx.y;
  char* Hc = (char*)&H[0][0];

  if (bx >= LSTM_XB) {     // ---- merged graph work: phase-2 scatter + rsq fills ----
    int e = (bx - LSTM_XB) + dir * LSTM_EXTRA;
    u16* colL = (u16*)Hc;                       // 16 KB
    int* curL = (int*)(Hc + 16384);             // 512 B
    if (e < 2 * NBUCK) {                        // phase-2: one block per (rel, bucket)
      int rel = e / NBUCK;
      int bk = e % NBUCK;
      const u32* bb = bucket + ((size_t)rel * NBUCK + bk) * BCAP;
      u16* col = rel ? col1 : col0;
      int cnt = gcur[rel * NBUCK + bk];
      if (cnt > BCAP) cnt = BCAP;
      if (tid < 128) curL[tid] = 0;
      __syncthreads();
      for (int i = tid; i < cnt; i += 256) {
        u32 r = bb[i];
        int dl = r & 127;
        int sv = (r >> 7) & 0xFFFF;
        int p = atomicAdd(&curL[dl], 1);
        if (p < DSTRIDE) colL[dl * DSTRIDE + p] = (u16)sv;
      }
      __syncthreads();
      const int node0 = bk << BSHIFT;
      for (int idx = tid; idx < 128 * (DSTRIDE / 2); idx += 256) {
        int row = idx >> 5;
        int node = node0 + row;
        if (node < N_NODES)
          ((uint*)(col + (size_t)node * DSTRIDE))[idx & 31] = ((const uint*)colL)[idx];
      }
      if (tid < 128) {
        int node = node0 + tid;
        if (node < N_NODES) {
          int c = curL[tid];
          cnt4[rel * 2 * N_NODES + N_NODES + node] = c;               // in-degree
          float cc = (c < 1) ? 1.f : (float)c;
          rsq4[rel * 2 * N_NODES + N_NODES + node] = __builtin_amdgcn_rsqf(cc);
        }
      }
    } else if (e < 2 * NBUCK + 391) {           // out-degree rsq: [0,N) and [2N,3N)
      int idx = (e - 2 * NBUCK) * 256 + tid;
      int i;
      if (idx < N_NODES) i = idx;
      else if (idx < 2 * N_NODES) i = idx + N_NODES;
      else return;
      int c = cnt4[i]; if (c < 1) c = 1;
      rsq4[i] = __builtin_amdgcn_rsqf((float)c);
    }
    return;
  }

  // ---- LSTM path ----
  const int w = tid >> 6;
  const int lane = tid & 63;
  const int quad = lane >> 4;
  const int lid = lane & 15;

  if (tid < 64) {
    int gid = bx * 64 + tid;
    int node = -1, len = 0;
    if (gid < nnodes) { node = perm[gid]; len = lens[node]; }
    permL[tid] = node; lensL[tid] = len;
  }
  {
    uint* Hz = (uint*)Hc;
    for (int i = tid; i < 2 * 64 * 72 / 2; i += 256) Hz[i] = 0u;   // zeroes data + token pad
  }
  __syncthreads();
  // per-step active-node cutoff (lens non-increasing within block since perm is len-sorted):
  // act(nd, step) <=> step < len[nd] <=> nd < cutL[step]
  if (tid <= SEQ_L) {
    int c = 0;
#pragma unroll 8
    for (int n = 0; n < 64; ++n) c += (lensL[n] > tid) ? 1 : 0;
    cutL[tid] = c;
  }
  // tokens into H row-padding (dir-reversal applied at load); unwritten entries stay 0
  for (int idx = tid; idx < 64 * SEQ_L; idx += 256) {
    int node = idx >> 5, tp = idx & 31;
    int len = lensL[node];
    if (tp < len) {
      int s = dir ? (len - 1 - tp) : tp;
      int i = s * 64 + node;
      Hc[(i >> 4) * 144 + 128 + (i & 15)] = (char)toksg[(size_t)permL[node] * SEQ_L + tp];
    }
  }
  __syncthreads();
  const int tmax = lensL[0];     // sorted descending -> first node holds block max

  const f16* Wd = Whh_h + (size_t)dir * 256 * 64;
  v8h Bf[4][2];
#pragma unroll
  for (int g = 0; g < 4; ++g)
#pragma unroll
    for (int kf = 0; kf < 2; ++kf)
      Bf[g][kf] = *(const v8h*)(Wd + (g * 64 + w * 16 + lid) * 64 + kf * 32 + quad * 8);

  float creg[16];
  f16 hreg[16];
#pragma unroll
  for (int i = 0; i < 16; ++i) { creg[i] = 0.f; hreg[i] = (f16)0.f; }

  const char* Xp = (const char*)(Xperm + (size_t)dir * 128 * 256);
  const uint xlane = (uint)((w * 16 + lid) * 16);   // byte offset of this thread's float4 slice

  for (int step = 0; step < tmax; ++step) {
    const int rb = step & 1, wb = rb ^ 1;
    const int cut = cutL[step];
#pragma unroll
    for (int mt = 0; mt < 4; ++mt) {
      // 4 tokens for this tile's node quad in one ds_read_b32 (from H row-pad)
      uint tok4 = *(const uint*)(Hc + (step * 4 + mt) * 144 + 128 + quad * 4);
      float4 xr[4];
#pragma unroll
      for (int r = 0; r < 4; ++r) {
        uint tok = (tok4 >> (8 * r)) & 255u;
        xr[r] = *(const float4*)(Xp + (tok << 10) + xlane);   // tok*1024B + lane slice
      }
      const f16* hb = &H[rb][0];
      int arow = (mt * 16 + lid) * 72 + quad * 8;
      v8h a0 = *(const v8h*)(hb + arow);
      v8h a1 = *(const v8h*)(hb + arow + 32);
      // x-contribution as MFMA C-init (acc row r = node quad*4+r, col = unit lid)
      v4f acc[4];
      acc[0] = (v4f){xr[0].x, xr[1].x, xr[2].x, xr[3].x};
      acc[1] = (v4f){xr[0].y, xr[1].y, xr[2].y, xr[3].y};
      acc[2] = (v4f){xr[0].z, xr[1].z, xr[2].z, xr[3].z};
      acc[3] = (v4f){xr[0].w, xr[1].w, xr[2].w, xr[3].w};
#pragma unroll
      for (int g = 0; g < 4; ++g) {
        acc[g] = MFMA16(a0, Bf[g][0], acc[g]);
        acc[g] = MFMA16(a1, Bf[g][1], acc[g]);
      }
#pragma unroll
      for (int r = 0; r < 4; ++r) {
        int idx = mt * 4 + r;
        int nd = mt * 16 + quad * 4 + r;
        bool act = nd < cut;
        float gi = acc[0][r];              // exp2-domain (pre-scaled by log2e)
        float gf = acc[1][r];
        float gG = acc[2][r];              // pre-scaled by 2*log2e
        float go = acc[3][r];
        float A = EXP2(-gi);
        float B = EXP2(-gf);
        float C = EXP2(-go);
        float D = EXP2(fminf(gG, GCLAMP));
        float sf = __builtin_amdgcn_rcpf(1.f + B);
        float sitg = (D - 1.f) * __builtin_amdgcn_rcpf((1.f + A) * (D + 1.f));
        float cn = sf * creg[idx] + sitg;
        float E = EXP2(fminf(cn * LOG2E2, GCLAMP));
        float hn = (E - 1.f) * __builtin_amdgcn_rcpf((1.f + C) * (E + 1.f));
        if (act) { creg[idx] = cn; hreg[idx] = (f16)hn; }
        H[wb][nd * 72 + w * 16 + lid] = hreg[idx];
      }
    }
    __syncthreads();
  }
#pragma unroll
  for (int mt = 0; mt < 4; ++mt)
#pragma unroll
    for (int r = 0; r < 4; ++r) {
      int nd = mt * 16 + quad * 4 + r;
      int gnode = permL[nd];
      if (gnode >= 0) {
        u16 bits; f16 hv = hreg[mt * 4 + r]; __builtin_memcpy(&bits, &hv, 2);
        hcat_h[(size_t)gnode * 128 + dir * 64 + w * 16 + lid] = bits;
      }
    }
}

// ---------------- fused steps 4+5: hcat -> h_url|emb (LDS only) -> Ps/Pu --------------------
__global__ __launch_bounds__(256) void fuse45_kernel(
    const u16* __restrict__ hcat,          // [N][128]
    const u16* __restrict__ Bfc,           // [64][128]
    const float* __restrict__ fcb,
    const int* __restrict__ ic, const int* __restrict__ ico, const int* __restrict__ isl,
    const u16* __restrict__ ech, const u16* __restrict__ ecoh, const u16* __restrict__ eslh,
    const u16* __restrict__ Bg0,           // [256 outcols][256]
    const float* __restrict__ rs0, const float* __restrict__ rs1,
    u16* __restrict__ Ps, u16* __restrict__ Pu, int nrows)
{
  __shared__ __align__(16) char smem[64 * 264 * 2];   // 33.8KB union
  u16* As1 = (u16*)smem;          // [64][136] hcat tile (phase 1)
  u16* As2 = (u16*)smem;          // [64][264] h tile (phase 2, aliases)
  float* Es = (float*)smem;       // [64][129] epilogue staging (phase 3, aliases)

  const int tid = threadIdx.x;
  const int w = tid >> 6, lane = tid & 63, quad = lane >> 4, lid = lane & 15;
  const int r0 = blockIdx.x * 64;

  for (int idx = tid; idx < 64 * 16; idx += 256) {
    int rn = idx >> 4, c8 = idx & 15;
    int row = r0 + rn;
    uint4 v = {0u, 0u, 0u, 0u};
    if (row < nrows) v = *(const uint4*)(hcat + (size_t)row * 128 + c8 * 8);
    *(uint4*)(As1 + rn * 136 + c8 * 8) = v;
  }
  __syncthreads();
  v4f acc1[4];
#pragma unroll
  for (int i = 0; i < 4; ++i) acc1[i] = (v4f){0.f, 0.f, 0.f, 0.f};
  for (int kb = 0; kb < 4; ++kb) {
    v8h a = *(const v8h*)((const f16*)As1 + (w * 16 + lid) * 136 + kb * 32 + quad * 8);
#pragma unroll
    for (int ct = 0; ct < 4; ++ct) {
      v8h b = *(const v8h*)((const f16*)Bfc + (size_t)(ct * 16 + lid) * 128 + kb * 32 + quad * 8);
      acc1[ct] = MFMA16(a, b, acc1[ct]);
    }
  }
  __syncthreads();                 // As1 reads done -> safe to overwrite (As2 aliases)
  // h_url = leaky(acc1 + fcb) -> As2 cols 0..63 (direct LDS scatter, C layout row=w*16+quad*4+r)
#pragma unroll
  for (int ct = 0; ct < 4; ++ct) {
    int col = ct * 16 + lid;
    float bv = fcb[col];
#pragma unroll
    for (int r = 0; r < 4; ++r) {
      int rn = w * 16 + quad * 4 + r;
      As2[rn * 264 + col] = f2h_bits(leakyf(acc1[ct][r] + bv));
    }
  }
  // embeddings -> As2 cols 64..255
  for (int idx = tid; idx < 64 * 192; idx += 256) {
    int rn = idx / 192, j = idx % 192;
    int row = r0 + rn;
    u16 v = 0;
    if (row < nrows) {
      if (j < 64)       v = ech [ic [row] * 64 + j];
      else if (j < 128) v = ecoh[ico[row] * 64 + (j - 64)];
      else              v = eslh[isl[row] * 64 + (j - 128)];
    }
    As2[rn * 264 + 64 + j] = v;
  }
  __syncthreads();
  v4f acc2[16];
#pragma unroll
  for (int i = 0; i < 16; ++i) acc2[i] = (v4f){0.f, 0.f, 0.f, 0.f};
  for (int kb = 0; kb < 8; ++kb) {
    v8h a = *(const v8h*)((const f16*)As2 + (w * 16 + lid) * 264 + kb * 32 + quad * 8);
#pragma unroll
    for (int ct = 0; ct < 16; ++ct) {
      v8h b = *(const v8h*)((const f16*)Bg0 + (size_t)(ct * 16 + lid) * 256 + kb * 32 + quad * 8);
      acc2[ct] = MFMA16(a, b, acc2[ct]);
    }
  }
#pragma unroll
  for (int h = 0; h < 2; ++h) {
    __syncthreads();
#pragma unroll
    for (int ct = 0; ct < 8; ++ct) {
      int ctg = h * 8 + ct;
#pragma unroll
      for (int r = 0; r < 4; ++r)
        Es[(w * 16 + quad * 4 + r) * 129 + ct * 16 + lid] = acc2[ctg][r];
    }
    __syncthreads();
    const float* rs = (h == 0) ? rs0 : rs1;
    u16* oh = (h == 0) ? Ps : Pu;
    for (int idx = tid; idx < 64 * 128; idx += 256) {
      int rn = idx >> 7, c = idx & 127;
      int row = r0 + rn;
      if (row < nrows)
        oh[(size_t)row * 128 + c] = f2h_bits(Es[rn * 129 + c] * rs[row]);
    }
  }
}

// ---------------- fused steps 8+9a: Acat -> F (LDS only) -> G12 ----------------------------
__global__ __launch_bounds__(256) void fuse89_kernel(
    const u16* __restrict__ Acat,          // [N][256]
    const u16* __restrict__ Bg1,           // [128 outcols][256]
    const float* __restrict__ b1s, const float* __restrict__ b1u,
    const u16* __restrict__ BW1,           // [256 outcols][128]
    u16* __restrict__ G12, int nrows)      // [N][256]
{
  __shared__ __align__(16) char smem[64 * 264 * 2];   // 33.8KB union
  u16* As1 = (u16*)smem;          // [64][264] Acat tile (phase 1)
  u16* As2 = (u16*)smem;          // [64][136] F tile (phase 2, aliases)
  float* Es = (float*)smem;       // [64][129] epilogue staging (phase 3, aliases)

  const int tid = threadIdx.x;
  const int w = tid >> 6, lane = tid & 63, quad = lane >> 4, lid = lane & 15;
  const int r0 = blockIdx.x * 64;

  for (int idx = tid; idx < 64 * 32; idx += 256) {
    int rn = idx >> 5, c8 = idx & 31;
    int row = r0 + rn;
    uint4 v = {0u, 0u, 0u, 0u};
    if (row < nrows) v = *(const uint4*)(Acat + (size_t)row * 256 + c8 * 8);
    *(uint4*)(As1 + rn * 264 + c8 * 8) = v;
  }
  __syncthreads();
  v4f acc1[8];
#pragma unroll
  for (int i = 0; i < 8; ++i) acc1[i] = (v4f){0.f, 0.f, 0.f, 0.f};
  for (int kb = 0; kb < 8; ++kb) {
    v8h a = *(const v8h*)((const f16*)As1 + (w * 16 + lid) * 264 + kb * 32 + quad * 8);
#pragma unroll
    for (int ct = 0; ct < 8; ++ct) {
      v8h b = *(const v8h*)((const f16*)Bg1 + (size_t)(ct * 16 + lid) * 256 + kb * 32 + quad * 8);
      acc1[ct] = MFMA16(a, b, acc1[ct]);
    }
  }
  __syncthreads();                 // As1 reads done -> safe to overwrite (As2 aliases)
  // F = leaky(acc1 + b1s + b1u) -> As2 [64][136] f16
#pragma unroll
  for (int ct = 0; ct < 8; ++ct) {
    int col = ct * 16 + lid;
    float bv = b1s[col] + b1u[col];
#pragma unroll
    for (int r = 0; r < 4; ++r) {
      int rn = w * 16 + quad * 4 + r;
      As2[rn * 136 + col] = f2h_bits(leakyf(acc1[ct][r] + bv));
    }
  }
  __syncthreads();
  v4f acc2[16];
#pragma unroll
  for (int i = 0; i < 16; ++i) acc2[i] = (v4f){0.f, 0.f, 0.f, 0.f};
  for (int kb = 0; kb < 4; ++kb) {
    v8h a = *(const v8h*)((const f16*)As2 + (w * 16 + lid) * 136 + kb * 32 + quad * 8);
#pragma unroll
    for (int ct = 0; ct < 16; ++ct) {
      v8h b = *(const v8h*)((const f16*)BW1 + (size_t)(ct * 16 + lid) * 128 + kb * 32 + quad * 8);
      acc2[ct] = MFMA16(a, b, acc2[ct]);
    }
  }
#pragma unroll
  for (int h = 0; h < 2; ++h) {
    __syncthreads();
#pragma unroll
    for (int ct = 0; ct < 8; ++ct) {
      int ctg = h * 8 + ct;
#pragma unroll
      for (int r = 0; r < 4; ++r)
        Es[(w * 16 + quad * 4 + r) * 129 + ct * 16 + lid] = acc2[ctg][r];
    }
    __syncthreads();
    for (int idx = tid; idx < 64 * 128; idx += 256) {
      int rn = idx >> 7, c = idx & 127;
      int row = r0 + rn;
      if (row < nrows)
        G12[(size_t)row * 256 + h * 128 + c] = f2h_bits(Es[rn * 129 + c]);
    }
  }
}

// ---------------- classifier edge kernel: z[e] = G1[src] + G2[dst] + b1 (+ BN sums) ---------
__global__ __launch_bounds__(256) void edge_cls_kernel(
    const int* __restrict__ esrc, const int* __restrict__ edst,
    const u16* __restrict__ G12,          // [N][256] f16: cols 0..127 = G1, 128..255 = G2
    const float* __restrict__ b1,
    u16* __restrict__ zh, float* __restrict__ bnsums, int ne)
{
  __shared__ float redS[512];
  __shared__ float redQ[512];
  const int tid = threadIdx.x;
  const int w = tid >> 6;
  const int lane = tid & 63;
  const uint* Gu = (const uint*)G12;      // row stride 128 uints
  float2 bsv = ((const float2*)b1)[lane];
  float s0 = 0.f, s1 = 0.f, q0 = 0.f, q1 = 0.f;
  const int e0 = blockIdx.x * 64 + w * 16;
#pragma unroll
  for (int k = 0; k < 16; ++k) {
    int e = e0 + k;
    if (e < ne) {
      int sv = esrc[e], dv = edst[e];
      uint a = Gu[(size_t)sv * 128 + lane];
      uint b = Gu[(size_t)dv * 128 + 64 + lane];
      float z0 = h2f((u16)a) + h2f((u16)b) + bsv.x;
      float z1 = h2f((u16)(a >> 16)) + h2f((u16)(b >> 16)) + bsv.y;
      ((uint*)zh)[(size_t)e * 64 + lane] = pack2h(z0, z1);
      s0 += z0; s1 += z1; q0 += z0 * z0; q1 += z1 * z1;
    }
  }
  redS[w * 128 + lane * 2 + 0] = s0;
  redS[w * 128 + lane * 2 + 1] = s1;
  redQ[w * 128 + lane * 2 + 0] = q0;
  redQ[w * 128 + lane * 2 + 1] = q1;
  __syncthreads();
  if (tid < 128) {
    float s = redS[tid] + redS[128 + tid] + redS[256 + tid] + redS[384 + tid];
    float q = redQ[tid] + redQ[128 + tid] + redQ[256 + tid] + redQ[384 + tid];
    float* bnp = bnsums + (size_t)(blockIdx.x & (BNREP - 1)) * 256;
    atomicAdd(&bnp[tid], s);
    atomicAdd(&bnp[128 + tid], q);
  }
}

// ---------------- layer0: fused dual gather + merge -> h1 (fp16), padded CSR (u16 cols) ------
__global__ __launch_bounds__(256) void gather_merge0_kernel(
    const u16* __restrict__ colS, const int* __restrict__ cntS, const u16* __restrict__ Ps,
    const u16* __restrict__ colU, const int* __restrict__ cntU, const u16* __restrict__ Pu,
    const float* __restrict__ rsS, const float* __restrict__ rsU,
    const float* __restrict__ bS, const float* __restrict__ bU,
    u16* __restrict__ outh, int nnodes)
{
  int wave = threadIdx.x >> 6;
  int lane = threadIdx.x & 63;
  int node = __builtin_amdgcn_readfirstlane(blockIdx.x * 4 + wave);
  if (node >= nnodes) return;
  const uint* PS2 = (const uint*)Ps;
  const uint* PU2 = (const uint*)Pu;
  float2 aS = make_float2(0.f, 0.f), aU = make_float2(0.f, 0.f);
  {
    const u16* col = colS + (size_t)node * DSTRIDE;
    int cnt = min(cntS[node], DSTRIDE);
    int e = 0;
    for (; e + 4 <= cnt; e += 4) {
      uint v0 = PS2[(size_t)col[e] * 64 + lane];
      uint v1 = PS2[(size_t)col[e + 1] * 64 + lane];
      uint v2 = PS2[(size_t)col[e + 2] * 64 + lane];
      uint v3 = PS2[(size_t)col[e + 3] * 64 + lane];
      aS.x += h2f((u16)v0) + h2f((u16)v1) + h2f((u16)v2) + h2f((u16)v3);
      aS.y += h2f((u16)(v0 >> 16)) + h2f((u16)(v1 >> 16)) + h2f((u16)(v2 >> 16)) + h2f((u16)(v3 >> 16));
    }
    for (; e < cnt; ++e) {
      uint v = PS2[(size_t)col[e] * 64 + lane];
      aS.x += h2f((u16)v); aS.y += h2f((u16)(v >> 16));
    }
  }
  {
    const u16* col = colU + (size_t)node * DSTRIDE;
    int cnt = min(cntU[node], DSTRIDE);
    int e = 0;
    for (; e + 4 <= cnt; e += 4) {
      uint v0 = PU2[(size_t)col[e] * 64 + lane];
      uint v1 = PU2[(size_t)col[e + 1] * 64 + lane];
      uint v2 = PU2[(size_t)col[e + 2] * 64 + lane];
      uint v3 = PU2[(size_t)col[e + 3] * 64 + lane];
      aU.x += h2f((u16)v0) + h2f((u16)v1) + h2f((u16)v2) + h2f((u16)v3);
      aU.y += h2f((u16)(v0 >> 16)) + h2f((u16)(v1 >> 16)) + h2f((u16)(v2 >> 16)) + h2f((u16)(v3 >> 16));
    }
    for (; e < cnt; ++e) {
      uint v = PU2[(size_t)col[e] * 64 + lane];
      aU.x += h2f((u16)v); aU.y += h2f((u16)(v >> 16));
    }
  }
  float rS = rsS[node], rU = rsU[node];
  float2 bsv = ((const float2*)bS)[lane];
  float2 buv = ((const float2*)bU)[lane];
  float o0 = leakyf(aS.x * rS + bsv.x + aU.x * rU + buv.x);
  float o1 = leakyf(aS.y * rS + bsv.y + aU.y * rU + buv.y);
  ((uint*)outh)[(size_t)node * 64 + lane] = pack2h(o0, o1);
}

// ---------------- layer1: fused dual gather -> A_cat fp16 [N][256] (scaled), u16 cols -------
__global__ __launch_bounds__(256) void gather_cat1_kernel(
    const u16* __restrict__ colS, const int* __restrict__ cntS,
    const u16* __restrict__ colU, const int* __restrict__ cntU,
    const u16* __restrict__ Fh,
    const float* __restrict__ rsoutS, const float* __restrict__ rsoutU,
    const float* __restrict__ rsinS, const float* __restrict__ rsinU,
    u16* __restrict__ Acat, int nnodes)
{
  int wave = threadIdx.x >> 6;
  int lane = threadIdx.x & 63;
  int node = __builtin_amdgcn_readfirstlane(blockIdx.x * 4 + wave);
  if (node >= nnodes) return;
  const uint* F2 = (const uint*)Fh;
  float2 aS = make_float2(0.f, 0.f), aU = make_float2(0.f, 0.f);
  {
    const u16* col = colS + (size_t)node * DSTRIDE;
    int cnt = min(cntS[node], DSTRIDE);
    int e = 0;
    for (; e + 2 <= cnt; e += 2) {
      int s0 = col[e], s1 = col[e + 1];
      float c0 = rsoutS[s0], c1 = rsoutS[s1];
      uint v0 = F2[(size_t)s0 * 64 + lane];
      uint v1 = F2[(size_t)s1 * 64 + lane];
      aS.x += c0 * h2f((u16)v0) + c1 * h2f((u16)v1);
      aS.y += c0 * h2f((u16)(v0 >> 16)) + c1 * h2f((u16)(v1 >> 16));
    }
    for (; e < cnt; ++e) {
      int s = col[e]; float c = rsoutS[s];
      uint v = F2[(size_t)s * 64 + lane];
      aS.x += c * h2f((u16)v); aS.y += c * h2f((u16)(v >> 16));
    }
  }
  {
    const u16* col = colU + (size_t)node * DSTRIDE;
    int cnt = min(cntU[node], DSTRIDE);
    int e = 0;
    for (; e + 2 <= cnt; e += 2) {
      int s0 = col[e], s1 = col[e + 1];
      float c0 = rsoutU[s0], c1 = rsoutU[s1];
      uint v0 = F2[(size_t)s0 * 64 + lane];
      uint v1 = F2[(size_t)s1 * 64 + lane];
      aU.x += c0 * h2f((u16)v0) + c1 * h2f((u16)v1);
      aU.y += c0 * h2f((u16)(v0 >> 16)) + c1 * h2f((u16)(v1 >> 16));
    }
    for (; e < cnt; ++e) {
      int s = col[e]; float c = rsoutU[s];
      uint v = F2[(size_t)s * 64 + lane];
      aU.x += c * h2f((u16)v); aU.y += c * h2f((u16)(v >> 16));
    }
  }
  float rs = rsinS[node], ru = rsinU[node];
  ((uint*)Acat)[(size_t)node * 128 + lane] = pack2h(aS.x * rs, aS.y * rs);
  ((uint*)Acat)[(size_t)node * 128 + 64 + lane] = pack2h(aU.x * ru, aU.y * ru);
}

// ---------------- output: BN(z) -> relu -> @W2 + b2 (BN coeffs from 64 bnsums replicas) -----
__global__ __launch_bounds__(256) void out_kernel(
    const u16* __restrict__ zh, const float* __restrict__ bnsums,
    const float* __restrict__ g, const float* __restrict__ bb, float M,
    const float* __restrict__ W2, const float* __restrict__ b2,
    void* __restrict__ out, int Mi, const int* __restrict__ flag)
{
  __shared__ float lds[128 * 65];
  __shared__ float red[64 * 8];
  __shared__ float ssL[256];
  const int tid = threadIdx.x;
  const int n = tid & 63;
  const int q = __builtin_amdgcn_readfirstlane(tid >> 6);
  const int r0 = blockIdx.x * 64;
  if (tid < 128) {
    float s = 0.f, s2 = 0.f;
#pragma unroll 8
    for (int r = 0; r < BNREP; ++r) {
      s  += bnsums[r * 256 + tid];
      s2 += bnsums[r * 256 + 128 + tid];
    }
    float mean = s / M;
    float var = s2 / M - mean * mean;
    float sc = g[tid] * __builtin_amdgcn_rsqf(var + 1e-5f);
    ssL[tid] = sc;
    ssL[128 + tid] = bb[tid] - mean * sc;
  }
  for (int idx = tid; idx < 64 * 128; idx += 256) {
    int rn = idx >> 7, j = idx & 127;
    int row = r0 + rn;
    lds[j * 65 + rn] = (row < Mi) ? h2f(zh[(size_t)row * 128 + j]) : 0.f;
  }
  __syncthreads();
  float a0 = 0.f, a1 = 0.f;
#pragma unroll 8
  for (int jj = 0; jj < 32; ++jj) {
    int j = q * 32 + jj;
    float y = lds[j * 65 + n] * ssL[j] + ssL[128 + j];
    y = y > 0.f ? y : 0.f;
    a0 += y * W2[j];
    a1 += y * W2[128 + j];
  }
  red[n * 8 + q * 2 + 0] = a0;
  red[n * 8 + q * 2 + 1] = a1;
  __syncthreads();
  if (q == 0 && (r0 + n) < Mi) {
    float o0 = red[n * 8] + red[n * 8 + 2] + red[n * 8 + 4] + red[n * 8 + 6] + b2[0];
    float o1 = red[n * 8 + 1] + red[n * 8 + 3] + red[n * 8 + 5] + red[n * 8 + 7] + b2[1];
    size_t oi = (size_t)(r0 + n) * 2;
    if (*flag) {
      ((bf16*)out)[oi + 0] = __float2bfloat16(o0);
      ((bf16*)out)[oi + 1] = __float2bfloat16(o1);
    } else {
      ((float*)out)[oi + 0] = o0;
      ((float*)out)[oi + 1] = o1;
    }
  }
}

// ==================================================================================
extern "C" void kernel_launch(void* const* d_in, const int* in_sizes, int n_in,
                              void* d_out, int out_size, void* d_ws, size_t ws_size,
                              hipStream_t stream) {
  (void)in_sizes; (void)n_in; (void)out_size; (void)ws_size;
  const int N = N_NODES;
  const int* inputs_s  = (const int*)d_in[0];
  const int* inputs_sm = (const int*)d_in[1];
  const int* inputs_c  = (const int*)d_in[2];
  const int* inputs_co = (const int*)d_in[3];
  const int* inputs_sl = (const int*)d_in[4];
  const int* sim_src   = (const int*)d_in[5];
  const int* sim_dst   = (const int*)d_in[6];
  const int* user_src  = (const int*)d_in[7];
  const int* user_dst  = (const int*)d_in[8];
  const int* esub_src  = (const int*)d_in[9];
  const int* esub_dst  = (const int*)d_in[10];

  // ---- workspace layout ----
  char* base = (char*)d_ws;
  size_t off = 0;
  auto alloc = [&](size_t bytes) -> char* {
    char* p = base + off;
    off += (bytes + 255) & ~(size_t)255;
    return p;
  };
  int* dflag    = (int*)alloc(256);
  f16* Whh_h    = (f16*)alloc(2 * 256 * 64 * 2);
  float* Xperm  = (float*)alloc(2 * 128 * 256 * 4);
  u16* Bfc      = (u16*)alloc(64 * 128 * 2);
  u16* BW1      = (u16*)alloc(256 * 128 * 2);
  u16* Bg0      = (u16*)alloc(256 * 256 * 2);
  u16* Bg1      = (u16*)alloc(128 * 256 * 2);
  u16* P_embc_h = (u16*)alloc(6464 * 2);
  u16* P_embco_h= (u16*)alloc(5888 * 2);
  u16* P_embs_h = (u16*)alloc(384 * 2);
  float* P_fcb  = (float*)alloc(64 * 4);
  float* P_b1   = (float*)alloc(128 * 4);
  float* P_g0sb = (float*)alloc(128 * 4);
  float* P_g0ub = (float*)alloc(128 * 4);
  float* P_g1sb = (float*)alloc(128 * 4);
  float* P_g1ub = (float*)alloc(128 * 4);
  float* P_bng  = (float*)alloc(128 * 4);
  float* P_bnb  = (float*)alloc(128 * 4);
  float* P_W2   = (float*)alloc(256 * 4);
  float* P_b2   = (float*)alloc(2 * 4);
  int* lens     = (int*)alloc((size_t)N * 4);
  int* perm     = (int*)alloc((size_t)N * 4);
  float* rsq4   = (float*)alloc((size_t)4 * N * 4);
  // ---- contiguous zero region (ONE memset): cnt4 | cnt33 | cur33 | gcur | bnsums[64] ----
  char* zbase   = alloc((size_t)4 * N * 4 + 4096 + BNREP * 256 * 4);
  int* cnt4     = (int*)zbase;                                    // [outS | inS | outU | inU]
  int* cnt33    = (int*)(zbase + (size_t)4 * N * 4);
  int* cur33    = cnt33 + 64;
  int* gcur     = (int*)(zbase + (size_t)4 * N * 4 + 512);        // 2*NBUCK ints (3128B)
  float* bnsums = (float*)(zbase + (size_t)4 * N * 4 + 4096);     // 64 replicas x 256 floats
  const size_t zbytes = (size_t)4 * N * 4 + 4096 + BNREP * 256 * 4;
  // big buffers:
  //   bufA = [ (unused 25.6MB) | col_sim 6.4MB (u16) | col_usr 6.4MB ]; zh (51.2MB) overwrites
  //   bufA at edge_cls (cols last read at gather_cat1 -- sequential stream, safe).
  //   bufC lifecycle: bucket buf (prep -> merged-LSTM phase2) -> Ps/Pu (fuse45 -> gather0)
  //   -> Acat (gather1 -> fuse89) -> G12 (fuse89 writes rows it alone staged; block-local
  //   read-before-write, no cross-block race) -> edge_cls.
  char* bufA = alloc((size_t)N * 256 * 4);
  char* bufB = alloc((size_t)N * 256 * 2);   // hcat_h [N][128]; later h1_h [N][128]
  char* bufC = alloc((size_t)N * 256 * 2);
  u16* zh      = (u16*)bufA;
  u16* col_sim = (u16*)(bufA + (size_t)N * 256 * 2);
  u16* col_usr = (u16*)(bufA + (size_t)N * 256 * 2 + (size_t)N * DSTRIDE * 2);
  u16* hcat_h = (u16*)bufB;
  u16* h1_h   = (u16*)bufB;
  u32* bucket = (u32*)bufC;                  // 2*NBUCK*BCAP*4 = 9.6MB <= 25.6MB
  u16* Ps_h   = (u16*)bufC;
  u16* Pu_h   = Ps_h + (size_t)N * 128;
  u16* Acat   = (u16*)bufC;
  u16* G12    = (u16*)bufC;                  // [N][256] f16 = 25.6MB (in-place over Acat)

  const int NB64 = (N + 63) / 64;              // 782
  const int NBZ  = (NE_SUB + 63) / 64;         // 3125

  // ---- 0. single memset for all accumulated regions ----
  hipMemsetAsync(zbase, 0, zbytes, stream);

  // ---- 1. merged prep + phase-1 edge binning (782 well-spread blocks) ----
  PrepArgs PA;
  PA.Whh_f = d_in[16]; PA.Whh_b = d_in[19]; PA.fc_W = d_in[21]; PA.cls_W1 = d_in[31];
  PA.g0sW = d_in[23]; PA.g0uW = d_in[25]; PA.g1sW = d_in[27]; PA.g1uW = d_in[29];
  PA.emb_cat = d_in[12]; PA.emb_country = d_in[13]; PA.emb_sl = d_in[14];
  PA.fc_b = d_in[22]; PA.cls_b1 = d_in[32]; PA.g0sb = d_in[24]; PA.g0ub = d_in[26];
  PA.g1sb = d_in[28]; PA.g1ub = d_in[30]; PA.bn_g = d_in[33]; PA.bn_b = d_in[34];
  PA.cls_W2 = d_in[35]; PA.cls_b2 = d_in[36];
  PA.emb_url = d_in[11]; PA.Wih_f = d_in[15]; PA.b_f = d_in[17]; PA.Wih_b = d_in[18]; PA.b_b = d_in[20];
  PA.Whh_h = Whh_h; PA.Bfc = Bfc; PA.BW1 = BW1; PA.Bg0 = Bg0; PA.Bg1 = Bg1;
  PA.embc_h = P_embc_h; PA.embco_h = P_embco_h; PA.embs_h = P_embs_h;
  PA.fcb = P_fcb; PA.b1 = P_b1; PA.g0sbP = P_g0sb; PA.g0ubP = P_g0ub; PA.g1sbP = P_g1sb; PA.g1ubP = P_g1ub;
  PA.bngP = P_bng; PA.bnbP = P_bnb; PA.W2P = P_W2; PA.b2P = P_b2;
  PA.dflag = dflag; PA.Xperm = Xperm;
  PA.sm = inputs_sm; PA.lens = lens; PA.cnt33 = cnt33;
  PA.s0 = sim_src; PA.d0 = sim_dst; PA.s1 = user_src; PA.d1 = user_dst;
  PA.cnt4 = cnt4; PA.gcur = gcur; PA.bucket = bucket;
  prep_graph_kernel<<<PG_BLOCKS, 256, 0, stream>>>(PA);

  // ---- 2. permfill (perm needed by LSTM) ----
  permfill_kernel<<<PF_BLOCKS, 256, 0, stream>>>(lens, cnt33, cur33, perm);

  // ---- 3. LSTM -> hcat_h; extra blocks run phase-2 scatter + rsq (hidden under LSTM) ----
  lstm_mfma_kernel<<<dim3(LSTM_XB + LSTM_EXTRA, 2), 256, 0, stream>>>(
      perm, lens, inputs_s, Xperm, Whh_h, hcat_h,
      bucket, gcur, col_sim, col_usr, cnt4, rsq4, N);

  // ---- 4+5 fused: hcat -> [h_url|emb] (LDS) -> layer0 dual projection -> Ps, Pu ----
  fuse45_kernel<<<NB64, 256, 0, stream>>>(
      hcat_h, Bfc, P_fcb, inputs_c, inputs_co, inputs_sl,
      P_embc_h, P_embco_h, P_embs_h, Bg0, rsq4, rsq4 + 2 * N, Ps_h, Pu_h, N);

  // ---- 6. layer0 gather+merge -> h1 ----
  gather_merge0_kernel<<<(N + 3) / 4, 256, 0, stream>>>(col_sim, cnt4 + N, Ps_h,
                                                        col_usr, cnt4 + 3 * N, Pu_h,
                                                        rsq4 + N, rsq4 + 3 * N, P_g0sb, P_g0ub, h1_h, N);

  // ---- 7. layer1 dual gather (scaled) -> Acat ----
  gather_cat1_kernel<<<(N + 3) / 4, 256, 0, stream>>>(col_sim, cnt4 + N, col_usr, cnt4 + 3 * N, h1_h,
                                                      rsq4, rsq4 + 2 * N, rsq4 + N, rsq4 + 3 * N, Acat, N);

  // ---- 8+9a fused: Acat -> F (LDS) -> G12 (in place over Acat) ----
  fuse89_kernel<<<NB64, 256, 0, stream>>>(Acat, Bg1, P_g1sb, P_g1ub, BW1, G12, N);

  // ---- 9b. z[e] = G1[src] + G2[dst] + b1 -> zh (+ BN partial sums, 64-way replicated) ----
  edge_cls_kernel<<<NBZ, 256, 0, stream>>>(esub_src, esub_dst, G12, P_b1, zh, bnsums, NE_SUB);

  // ---- 10. BN + relu + W2 (folds the 64 replicas) ----
  out_kernel<<<NBZ, 256, 0, stream>>>(zh, bnsums, P_bng, P_bnb, (float)NE_SUB,
                                      P_W2, P_b2, d_out, NE_SUB, dflag);
}

// Round 12
// 931.038 us; speedup vs baseline: 1.0536x; 1.0536x over previous
//
#include <hip/hip_runtime.h>
#include <hip/hip_bf16.h>
#include <stdint.h>

// Problem constants
#define N_NODES 50000
#define SEQ_L   32
#define NE_BIG  800000
#define NE_SUB  200000
#define DSTRIDE 64          // padded-CSR slots per node (Poisson(16) in-degree; P(>64) ~ 2e-18)
#define BNREP   64          // bnsums replication factor (kills the 800K-atomics-to-16-lines funnel)

typedef __hip_bfloat16 bf16;
typedef unsigned short u16;
typedef unsigned int u32;
typedef _Float16 f16;
typedef _Float16 v8h __attribute__((ext_vector_type(8)));  // 8 f16 in 4 VGPRs (MFMA A/B frag)
typedef float v4f __attribute__((ext_vector_type(4)));     // MFMA C/D frag

// fast exp2 -> single v_exp_f32 (weights are pre-scaled by log2e so gates are in exp2 domain)
#if __has_builtin(__builtin_amdgcn_exp2f)
#define EXP2(x) __builtin_amdgcn_exp2f(x)
#else
extern "C" __device__ float __ocml_native_exp2_f32(float);
#define EXP2(x) __ocml_native_exp2_f32(x)
#endif
#define LOG2E  1.4426950408889634f
#define LOG2E2 2.8853900817779268f
#define GCLAMP 43.280851226668902f   // 15 * 2*log2e

#define MFMA16(a, b, c) __builtin_amdgcn_mfma_f32_16x16x32_f16(a, b, c, 0, 0, 0)

__device__ __forceinline__ float b2f(bf16 x) { return __bfloat162float(x); }
__device__ __forceinline__ float leakyf(float v) { return v >= 0.f ? v : 0.01f * v; }
__device__ __forceinline__ u16 f2h_bits(float x) { f16 h = (f16)x; u16 b; __builtin_memcpy(&b, &h, 2); return b; }
__device__ __forceinline__ float h2f(u16 b) { f16 h; __builtin_memcpy(&h, &b, 2); return (float)h; }
__device__ __forceinline__ uint pack2h(float a, float b) { return (uint)f2h_bits(a) | ((uint)f2h_bits(b) << 16); }

// load float input element i, dtype per flag (1 = bf16 storage, 0 = fp32 storage)
__device__ __forceinline__ float ldf(const void* p, int i, int isbf) {
  return isbf ? b2f(((const bf16*)p)[i]) : ((const float*)p)[i];
}

// Per-block dtype self-detection: sample 256 even-index uint16s of emb_url.
__device__ __forceinline__ int detect_isbf(const u16* __restrict__ u) {
  __shared__ int insane;
  if (threadIdx.x == 0) insane = 0;
  __syncthreads();
  int expo = (u[threadIdx.x * 2] >> 7) & 0xFF;
  if (expo >= 147) atomicAdd(&insane, 1);
  __syncthreads();
  return insane == 0;
}

// ---------------- binned graph build constants ----------------
// r12: P1_EPT back to 32 (r11's 8 was neutral-to-negative -> occupancy-hole theory refuted;
// 8192-edge chunks with long bucket runs write fewer partial lines and won at 973us).
#define NBUCK   391                 // ceil(50000/128) buckets of 128 nodes
#define BSHIFT  7
#define BCAP    3072                // per-bucket capacity; mean 2048, sd~45 -> +22 sigma
#define P1_EPT   32
#define P1_CHUNK (256 * P1_EPT)     // 8192 edges per block
#define P1_NCH   ((NE_BIG + P1_CHUNK - 1) / P1_CHUNK)   // 98
#define P1_BLOCKS (P1_NCH * 2)      // x2 relations = 196
#define LSTM_XB  782                // LSTM blocks per dir
#define LSTM_EXTRA 587              // ceil((2*NBUCK + 391)/2): phase2 + rsq blocks per y-plane

// ---------------- PREP + PHASE-1 EDGE BINNING ----------------
// Zeroing of cnt4/cnt33/cur33/gcur/bnsums happens via ONE hipMemsetAsync before this kernel.
struct PrepArgs {
  const void* Whh_f; const void* Whh_b; const void* fc_W; const void* cls_W1;
  const void* g0sW; const void* g0uW; const void* g1sW; const void* g1uW;
  const void* emb_cat; const void* emb_country; const void* emb_sl;
  const void* fc_b; const void* cls_b1; const void* g0sb; const void* g0ub;
  const void* g1sb; const void* g1ub; const void* bn_g; const void* bn_b;
  const void* cls_W2; const void* cls_b2;
  const void* emb_url; const void* Wih_f; const void* b_f; const void* Wih_b; const void* b_b;
  f16* Whh_h; u16* Bfc; u16* BW1; u16* Bg0; u16* Bg1;
  u16* embc_h; u16* embco_h; u16* embs_h;
  float* fcb; float* b1; float* g0sbP; float* g0ubP; float* g1sbP; float* g1ubP;
  float* bngP; float* bnbP; float* W2P; float* b2P;
  int* dflag;
  float* Xperm;
  // graph part
  const int* sm; int* lens; int* cnt33;
  const int* s0; const int* d0; const int* s1; const int* d1;
  int* cnt4; int* gcur; u32* bucket;
};

__global__ __launch_bounds__(256) void prep_graph_kernel(PrepArgs A) {
  const int bid = blockIdx.x;
  const int t = threadIdx.x;

  __shared__ u32 stage[P1_CHUNK];          // 32 KB, bucket-ordered packed records
  __shared__ int hcnt[NBUCK];
  __shared__ int hstart[NBUCK];
  __shared__ int gbase[NBUCK];
  __shared__ int scanbuf[512];

  if (bid < P1_BLOCKS) {   // ---- phase-1: bin edges by dst>>7 ----
    const int rel = bid & 1;
    const int chunk = bid >> 1;
    const int* s = rel ? A.s1 : A.s0;
    const int* d = rel ? A.d1 : A.d0;
    int* outdeg = A.cnt4 + (size_t)rel * 2 * N_NODES;
    int* gcur = A.gcur + rel * NBUCK;
    u32* bbuf = A.bucket + (size_t)rel * NBUCK * BCAP;
    const int e0 = chunk * P1_CHUNK;
    const int cn = min(NE_BIG - e0, P1_CHUNK);

    for (int b = t; b < NBUCK; b += 256) hcnt[b] = 0;
    __syncthreads();
    // pass A: out-degree atomics (no-return) + local histogram
#pragma unroll
    for (int k = 0; k < P1_EPT; ++k) {
      int i = t + k * 256;
      if (i < cn) {
        int sv = s[e0 + i], dv = d[e0 + i];
        atomicAdd(&outdeg[sv], 1);
        atomicAdd(&hcnt[dv >> BSHIFT], 1);
      }
    }
    __syncthreads();
    // pass B: inclusive Hillis-Steele scan over 512 (2 elems/thread)
    scanbuf[t] = (t < NBUCK) ? hcnt[t] : 0;
    scanbuf[t + 256] = (t + 256 < NBUCK) ? hcnt[t + 256] : 0;
    __syncthreads();
    for (int off = 1; off < 512; off <<= 1) {
      int a0 = (t >= off) ? scanbuf[t - off] : 0;
      int a1 = (t + 256 >= off) ? scanbuf[t + 256 - off] : 0;
      __syncthreads();
      scanbuf[t] += a0;
      scanbuf[t + 256] += a1;
      __syncthreads();
    }
    // reserve global ranges (1 atomic per non-empty bucket), reset live cursors
    for (int b = t; b < NBUCK; b += 256) {
      int c = hcnt[b];
      int st = scanbuf[b] - c;       // exclusive prefix
      hstart[b] = st;
      gbase[b] = (c > 0) ? atomicAdd(&gcur[b], c) : 0;
      scanbuf[b] = st;               // live cursor for pass C
    }
    __syncthreads();
    // pass C: re-read edges (L2-hot), place bucket-ordered into stage
#pragma unroll
    for (int k = 0; k < P1_EPT; ++k) {
      int i = t + k * 256;
      if (i < cn) {
        int sv = s[e0 + i], dv = d[e0 + i];
        int b = dv >> BSHIFT;
        int pos = atomicAdd(&scanbuf[b], 1);
        stage[pos] = ((u32)b << 23) | ((u32)sv << 7) | (u32)(dv & 127);
      }
    }
    __syncthreads();
    // pass D: contiguous per-bucket runs out to global bucket segments
    for (int i = t; i < cn; i += 256) {
      u32 r = stage[i];
      int b = r >> 23;
      int o = gbase[b] + (i - hstart[b]);
      if (o < BCAP) bbuf[(size_t)b * BCAP + o] = r;
    }
    return;
  }

  const int b = bid - P1_BLOCKS;

  if (b >= 990) {    // ---- seq lens: 196 blocks ----
    int i = (b - 990) * 256 + t;
    if (i >= N_NODES) return;
    int len = 0;
#pragma unroll
    for (int tt = 0; tt < SEQ_L; ++tt) len += __builtin_nontemporal_load(A.sm + i * SEQ_L + tt);
    A.lens[i] = len;
    atomicAdd(&A.cnt33[len], 1);
    return;
  }

  const int isbf = detect_isbf((const u16*)A.emb_url);
  auto cpy = [&](const void* s, float* d, int n, int boff) {
    int i = (b - boff) * 256 + t;
    if (i < n) d[i] = ldf(s, i, isbf);
  };
  auto cvh = [&](const void* s, u16* d, int n, int boff) {
    int i = (b - boff) * 256 + t;
    if (i < n) d[i] = f2h_bits(ldf(s, i, isbf));
  };
  // Whh convert with log2e prescale (gate g=rows[128,192) gets 2*log2e): exp2-domain gates
  auto cvhW = [&](const void* s, u16* d, int boff) {
    int i = (b - boff) * 256 + t;     // i in [0,16384)
    float sc = ((i >> 12) == 2) ? LOG2E2 : LOG2E;   // i>>6 = row, row>>6 = gate
    d[i] = f2h_bits(ldf(s, i, isbf) * sc);
  };
  auto trh = [&](const void* s, u16* d, int R, int C, int KOFF, int boff) {  // d[c*256+KOFF+r]
    int i = (b - boff) * 256 + t;
    if (i < R * C) { int r = i / C, c = i % C; d[c * 256 + KOFF + r] = f2h_bits(ldf(s, i, isbf)); }
  };
  if      (b <   64) cvhW(A.Whh_f, (u16*)A.Whh_h, 0);
  else if (b <  128) cvhW(A.Whh_b, (u16*)(A.Whh_h + 16384), 64);
  else if (b <  160) cvh(A.fc_W, A.Bfc, 8192, 128);
  else if (b <  288) {
    // cls_W1 (128x256) -> Bcat [256 cols][K=128]: col j = W1[j][0:128] (G1 half),
    // col 128+j = W1[j][128:256] (G2 half). Enables the gather-free classifier
    // z[e] = G1[src] + G2[dst] + b1.
    int i = (b - 160) * 256 + t;     // i < 32768
    int j = i >> 8, k = i & 255;
    A.BW1[(size_t)(((k >> 7) * 128 + j) * 128 + (k & 127))] = f2h_bits(ldf(A.cls_W1, i, isbf));
  }
  else if (b <  416) trh(A.g0sW, A.Bg0, 256, 128, 0, 288);
  else if (b <  544) trh(A.g0uW, A.Bg0 + 128 * 256, 256, 128, 0, 416);
  else if (b <  608) trh(A.g1sW, A.Bg1, 128, 128, 0, 544);
  else if (b <  672) trh(A.g1uW, A.Bg1, 128, 128, 128, 608);
  else if (b <  698) cvh(A.emb_cat, A.embc_h, 6464, 672);
  else if (b <  721) cvh(A.emb_country, A.embco_h, 5888, 698);
  else if (b <  723) cvh(A.emb_sl, A.embs_h, 384, 721);
  else if (b <  724) cpy(A.fc_b, A.fcb, 64, 723);
  else if (b <  725) cpy(A.cls_b1, A.b1, 128, 724);
  else if (b <  726) cpy(A.g0sb, A.g0sbP, 128, 725);
  else if (b <  727) cpy(A.g0ub, A.g0ubP, 128, 726);
  else if (b <  728) cpy(A.g1sb, A.g1sbP, 128, 727);
  else if (b <  729) cpy(A.g1ub, A.g1ubP, 128, 728);
  else if (b <  730) cpy(A.bn_g, A.bngP, 128, 729);
  else if (b <  731) cpy(A.bn_b, A.bnbP, 128, 730);
  else if (b <  732) cpy(A.cls_W2, A.W2P, 256, 731);
  else if (b <  733) { cpy(A.cls_b2, A.b2P, 2, 732); if (t == 0) A.dflag[0] = isbf; }
  else if (b <  989) {                                   // xproj: 256 blocks
    int bb = b - 733;
    int dir = bb >> 7;
    int v = bb & 127;
    const void* Wih = dir ? A.Wih_b : A.Wih_f;
    const void* bias = dir ? A.b_b : A.b_f;
    __shared__ float embL[64];
    if (t < 64) embL[t] = ldf(A.emb_url, v * 64 + t, isbf);
    __syncthreads();
    float acc = ldf(bias, t, isbf);
#pragma unroll 8
    for (int j = 0; j < 64; ++j) acc += embL[j] * ldf(Wih, t * 64 + j, isbf);
    int g = t >> 6, unit = t & 63;
    float sc = (g == 2) ? LOG2E2 : LOG2E;                // exp2-domain prescale (matches Whh)
    A.Xperm[(size_t)dir * 128 * 256 + v * 256 + unit * 4 + g] = acc * sc;
  }
}
#define PG_BLOCKS (P1_BLOCKS + 1186)

// ---------------- permfill (self-prefix over 33 buckets, descending) ----------------
__global__ __launch_bounds__(256) void permfill_kernel(
    const int* __restrict__ lens, const int* __restrict__ cnt33, int* __restrict__ cur33,
    int* __restrict__ perm)
{
  int i = blockIdx.x * 256 + threadIdx.x;
  if (i >= N_NODES) return;
  int len = lens[i];
  int base = 0;
  for (int l = len + 1; l <= SEQ_L; ++l) base += cnt33[l];   // longest-first
  int p = atomicAdd(&cur33[len], 1);
  perm[base + p] = i;
}
#define PF_BLOCKS 196

// ---------------- MFMA LSTM + merged PHASE-2 scatter / rsq fills --------------------------
__global__ __launch_bounds__(256, 4) void lstm_mfma_kernel(
    const int* __restrict__ perm, const int* __restrict__ lens,
    const int* __restrict__ toksg,         // [N][32]
    const float* __restrict__ Xperm,       // [2][128][64][4]  (bias folded, gate-permuted, exp2-scaled)
    const f16* __restrict__ Whh_h,         // [2][256][64] fp16 (exp2-scaled)
    u16* __restrict__ hcat_h,              // [N][128] fp16 bits
    const u32* __restrict__ bucket, const int* __restrict__ gcur,
    u16* __restrict__ col0, u16* __restrict__ col1,
    int* __restrict__ cnt4, float* __restrict__ rsq4,
    int nnodes)
{
  // H rows: 64 data f16 + 8 pad f16 (bank skew). The 128 rows x 16 pad bytes = 2048B host
  // the token table: entry i = step*64+node lives at byte (i>>4)*144 + 128 + (i&15).
  __shared__ __align__(16) f16 H[2][64 * 72];   // 18.4 KB total (incl. token pad)
  __shared__ int permL[64];
  __shared__ int lensL[64];
  __shared__ int cutL[SEQ_L + 1];
  const int tid = threadIdx.x;
  const int bx = blockIdx.x;
  const int dir = blockIdx.y;
  char* Hc = (char*)&H[0][0];

  if (bx >= LSTM_XB) {     // ---- merged graph work: phase-2 scatter + rsq fills ----
    int e = (bx - LSTM_XB) + dir * LSTM_EXTRA;
    u16* colL = (u16*)Hc;                       // 16 KB
    int* curL = (int*)(Hc + 16384);             // 512 B
    if (e < 2 * NBUCK) {                        // phase-2: one block per (rel, bucket)
      int rel = e / NBUCK;
      int bk = e % NBUCK;
      const u32* bb = bucket + ((size_t)rel * NBUCK + bk) * BCAP;
      u16* col = rel ? col1 : col0;
      int cnt = gcur[rel * NBUCK + bk];
      if (cnt > BCAP) cnt = BCAP;
      if (tid < 128) curL[tid] = 0;
      __syncthreads();
      for (int i = tid; i < cnt; i += 256) {
        u32 r = bb[i];
        int dl = r & 127;
        int sv = (r >> 7) & 0xFFFF;
        int p = atomicAdd(&curL[dl], 1);
        if (p < DSTRIDE) colL[dl * DSTRIDE + p] = (u16)sv;
      }
      __syncthreads();
      const int node0 = bk << BSHIFT;
      for (int idx = tid; idx < 128 * (DSTRIDE / 2); idx += 256) {
        int row = idx >> 5;
        int node = node0 + row;
        if (node < N_NODES)
          ((uint*)(col + (size_t)node * DSTRIDE))[idx & 31] = ((const uint*)colL)[idx];
      }
      if (tid < 128) {
        int node = node0 + tid;
        if (node < N_NODES) {
          int c = curL[tid];
          cnt4[rel * 2 * N_NODES + N_NODES + node] = c;               // in-degree
          float cc = (c < 1) ? 1.f : (float)c;
          rsq4[rel * 2 * N_NODES + N_NODES + node] = __builtin_amdgcn_rsqf(cc);
        }
      }
    } else if (e < 2 * NBUCK + 391) {           // out-degree rsq: [0,N) and [2N,3N)
      int idx = (e - 2 * NBUCK) * 256 + tid;
      int i;
      if (idx < N_NODES) i = idx;
      else if (idx < 2 * N_NODES) i = idx + N_NODES;
      else return;
      int c = cnt4[i]; if (c < 1) c = 1;
      rsq4[i] = __builtin_amdgcn_rsqf((float)c);
    }
    return;
  }

  // ---- LSTM path ----
  const int w = tid >> 6;
  const int lane = tid & 63;
  const int quad = lane >> 4;
  const int lid = lane & 15;

  if (tid < 64) {
    int gid = bx * 64 + tid;
    int node = -1, len = 0;
    if (gid < nnodes) { node = perm[gid]; len = lens[node]; }
    permL[tid] = node; lensL[tid] = len;
  }
  {
    uint* Hz = (uint*)Hc;
    for (int i = tid; i < 2 * 64 * 72 / 2; i += 256) Hz[i] = 0u;   // zeroes data + token pad
  }
  __syncthreads();
  // per-step active-node cutoff (lens non-increasing within block since perm is len-sorted):
  // act(nd, step) <=> step < len[nd] <=> nd < cutL[step]
  if (tid <= SEQ_L) {
    int c = 0;
#pragma unroll 8
    for (int n = 0; n < 64; ++n) c += (lensL[n] > tid) ? 1 : 0;
    cutL[tid] = c;
  }
  // tokens into H row-padding (dir-reversal applied at load); unwritten entries stay 0
  for (int idx = tid; idx < 64 * SEQ_L; idx += 256) {
    int node = idx >> 5, tp = idx & 31;
    int len = lensL[node];
    if (tp < len) {
      int s = dir ? (len - 1 - tp) : tp;
      int i = s * 64 + node;
      Hc[(i >> 4) * 144 + 128 + (i & 15)] = (char)toksg[(size_t)permL[node] * SEQ_L + tp];
    }
  }
  __syncthreads();
  const int tmax = lensL[0];     // sorted descending -> first node holds block max

  const f16* Wd = Whh_h + (size_t)dir * 256 * 64;
  v8h Bf[4][2];
#pragma unroll
  for (int g = 0; g < 4; ++g)
#pragma unroll
    for (int kf = 0; kf < 2; ++kf)
      Bf[g][kf] = *(const v8h*)(Wd + (g * 64 + w * 16 + lid) * 64 + kf * 32 + quad * 8);

  float creg[16];
  f16 hreg[16];
#pragma unroll
  for (int i = 0; i < 16; ++i) { creg[i] = 0.f; hreg[i] = (f16)0.f; }

  const char* Xp = (const char*)(Xperm + (size_t)dir * 128 * 256);
  const uint xlane = (uint)((w * 16 + lid) * 16);   // byte offset of this thread's float4 slice

  for (int step = 0; step < tmax; ++step) {
    const int rb = step & 1, wb = rb ^ 1;
    const int cut = cutL[step];
#pragma unroll
    for (int mt = 0; mt < 4; ++mt) {
      // 4 tokens for this tile's node quad in one ds_read_b32 (from H row-pad)
      uint tok4 = *(const uint*)(Hc + (step * 4 + mt) * 144 + 128 + quad * 4);
      float4 xr[4];
#pragma unroll
      for (int r = 0; r < 4; ++r) {
        uint tok = (tok4 >> (8 * r)) & 255u;
        xr[r] = *(const float4*)(Xp + (tok << 10) + xlane);   // tok*1024B + lane slice
      }
      const f16* hb = &H[rb][0];
      int arow = (mt * 16 + lid) * 72 + quad * 8;
      v8h a0 = *(const v8h*)(hb + arow);
      v8h a1 = *(const v8h*)(hb + arow + 32);
      // x-contribution as MFMA C-init (acc row r = node quad*4+r, col = unit lid)
      v4f acc[4];
      acc[0] = (v4f){xr[0].x, xr[1].x, xr[2].x, xr[3].x};
      acc[1] = (v4f){xr[0].y, xr[1].y, xr[2].y, xr[3].y};
      acc[2] = (v4f){xr[0].z, xr[1].z, xr[2].z, xr[3].z};
      acc[3] = (v4f){xr[0].w, xr[1].w, xr[2].w, xr[3].w};
#pragma unroll
      for (int g = 0; g < 4; ++g) {
        acc[g] = MFMA16(a0, Bf[g][0], acc[g]);
        acc[g] = MFMA16(a1, Bf[g][1], acc[g]);
      }
#pragma unroll
      for (int r = 0; r < 4; ++r) {
        int idx = mt * 4 + r;
        int nd = mt * 16 + quad * 4 + r;
        bool act = nd < cut;
        float gi = acc[0][r];              // exp2-domain (pre-scaled by log2e)
        float gf = acc[1][r];
        float gG = acc[2][r];              // pre-scaled by 2*log2e
        float go = acc[3][r];
        float A = EXP2(-gi);
        float B = EXP2(-gf);
        float C = EXP2(-go);
        float D = EXP2(fminf(gG, GCLAMP));
        float sf = __builtin_amdgcn_rcpf(1.f + B);
        float sitg = (D - 1.f) * __builtin_amdgcn_rcpf((1.f + A) * (D + 1.f));
        float cn = sf * creg[idx] + sitg;
        float E = EXP2(fminf(cn * LOG2E2, GCLAMP));
        float hn = (E - 1.f) * __builtin_amdgcn_rcpf((1.f + C) * (E + 1.f));
        if (act) { creg[idx] = cn; hreg[idx] = (f16)hn; }
        H[wb][nd * 72 + w * 16 + lid] = hreg[idx];
      }
    }
    __syncthreads();
  }
#pragma unroll
  for (int mt = 0; mt < 4; ++mt)
#pragma unroll
    for (int r = 0; r < 4; ++r) {
      int nd = mt * 16 + quad * 4 + r;
      int gnode = permL[nd];
      if (gnode >= 0) {
        u16 bits; f16 hv = hreg[mt * 4 + r]; __builtin_memcpy(&bits, &hv, 2);
        hcat_h[(size_t)gnode * 128 + dir * 64 + w * 16 + lid] = bits;
      }
    }
}

// ---------------- fused steps 4+5: hcat -> h_url|emb (LDS only) -> Ps/Pu --------------------
__global__ __launch_bounds__(256) void fuse45_kernel(
    const u16* __restrict__ hcat,          // [N][128]
    const u16* __restrict__ Bfc,           // [64][128]
    const float* __restrict__ fcb,
    const int* __restrict__ ic, const int* __restrict__ ico, const int* __restrict__ isl,
    const u16* __restrict__ ech, const u16* __restrict__ ecoh, const u16* __restrict__ eslh,
    const u16* __restrict__ Bg0,           // [256 outcols][256]
    const float* __restrict__ rs0, const float* __restrict__ rs1,
    u16* __restrict__ Ps, u16* __restrict__ Pu, int nrows)
{
  __shared__ __align__(16) char smem[64 * 264 * 2];   // 33.8KB union
  u16* As1 = (u16*)smem;          // [64][136] hcat tile (phase 1)
  u16* As2 = (u16*)smem;          // [64][264] h tile (phase 2, aliases)
  float* Es = (float*)smem;       // [64][129] epilogue staging (phase 3, aliases)

  const int tid = threadIdx.x;
  const int w = tid >> 6, lane = tid & 63, quad = lane >> 4, lid = lane & 15;
  const int r0 = blockIdx.x * 64;

  for (int idx = tid; idx < 64 * 16; idx += 256) {
    int rn = idx >> 4, c8 = idx & 15;
    int row = r0 + rn;
    uint4 v = {0u, 0u, 0u, 0u};
    if (row < nrows) v = *(const uint4*)(hcat + (size_t)row * 128 + c8 * 8);
    *(uint4*)(As1 + rn * 136 + c8 * 8) = v;
  }
  __syncthreads();
  v4f acc1[4];
#pragma unroll
  for (int i = 0; i < 4; ++i) acc1[i] = (v4f){0.f, 0.f, 0.f, 0.f};
  for (int kb = 0; kb < 4; ++kb) {
    v8h a = *(const v8h*)((const f16*)As1 + (w * 16 + lid) * 136 + kb * 32 + quad * 8);
#pragma unroll
    for (int ct = 0; ct < 4; ++ct) {
      v8h b = *(const v8h*)((const f16*)Bfc + (size_t)(ct * 16 + lid) * 128 + kb * 32 + quad * 8);
      acc1[ct] = MFMA16(a, b, acc1[ct]);
    }
  }
  __syncthreads();                 // As1 reads done -> safe to overwrite (As2 aliases)
  // h_url = leaky(acc1 + fcb) -> As2 cols 0..63 (direct LDS scatter, C layout row=w*16+quad*4+r)
#pragma unroll
  for (int ct = 0; ct < 4; ++ct) {
    int col = ct * 16 + lid;
    float bv = fcb[col];
#pragma unroll
    for (int r = 0; r < 4; ++r) {
      int rn = w * 16 + quad * 4 + r;
      As2[rn * 264 + col] = f2h_bits(leakyf(acc1[ct][r] + bv));
    }
  }
  // embeddings -> As2 cols 64..255
  for (int idx = tid; idx < 64 * 192; idx += 256) {
    int rn = idx / 192, j = idx % 192;
    int row = r0 + rn;
    u16 v = 0;
    if (row < nrows) {
      if (j < 64)       v = ech [ic [row] * 64 + j];
      else if (j < 128) v = ecoh[ico[row] * 64 + (j - 64)];
      else              v = eslh[isl[row] * 64 + (j - 128)];
    }
    As2[rn * 264 + 64 + j] = v;
  }
  __syncthreads();
  v4f acc2[16];
#pragma unroll
  for (int i = 0; i < 16; ++i) acc2[i] = (v4f){0.f, 0.f, 0.f, 0.f};
  for (int kb = 0; kb < 8; ++kb) {
    v8h a = *(const v8h*)((const f16*)As2 + (w * 16 + lid) * 264 + kb * 32 + quad * 8);
#pragma unroll
    for (int ct = 0; ct < 16; ++ct) {
      v8h b = *(const v8h*)((const f16*)Bg0 + (size_t)(ct * 16 + lid) * 256 + kb * 32 + quad * 8);
      acc2[ct] = MFMA16(a, b, acc2[ct]);
    }
  }
#pragma unroll
  for (int h = 0; h < 2; ++h) {
    __syncthreads();
#pragma unroll
    for (int ct = 0; ct < 8; ++ct) {
      int ctg = h * 8 + ct;
#pragma unroll
      for (int r = 0; r < 4; ++r)
        Es[(w * 16 + quad * 4 + r) * 129 + ct * 16 + lid] = acc2[ctg][r];
    }
    __syncthreads();
    const float* rs = (h == 0) ? rs0 : rs1;
    u16* oh = (h == 0) ? Ps : Pu;
    for (int idx = tid; idx < 64 * 128; idx += 256) {
      int rn = idx >> 7, c = idx & 127;
      int row = r0 + rn;
      if (row < nrows)
        oh[(size_t)row * 128 + c] = f2h_bits(Es[rn * 129 + c] * rs[row]);
    }
  }
}

// ---------------- fused steps 8+9a: Acat -> F (LDS only) -> G12 ----------------------------
__global__ __launch_bounds__(256) void fuse89_kernel(
    const u16* __restrict__ Acat,          // [N][256]
    const u16* __restrict__ Bg1,           // [128 outcols][256]
    const float* __restrict__ b1s, const float* __restrict__ b1u,
    const u16* __restrict__ BW1,           // [256 outcols][128]
    u16* __restrict__ G12, int nrows)      // [N][256]
{
  __shared__ __align__(16) char smem[64 * 264 * 2];   // 33.8KB union
  u16* As1 = (u16*)smem;          // [64][264] Acat tile (phase 1)
  u16* As2 = (u16*)smem;          // [64][136] F tile (phase 2, aliases)
  float* Es = (float*)smem;       // [64][129] epilogue staging (phase 3, aliases)

  const int tid = threadIdx.x;
  const int w = tid >> 6, lane = tid & 63, quad = lane >> 4, lid = lane & 15;
  const int r0 = blockIdx.x * 64;

  for (int idx = tid; idx < 64 * 32; idx += 256) {
    int rn = idx >> 5, c8 = idx & 31;
    int row = r0 + rn;
    uint4 v = {0u, 0u, 0u, 0u};
    if (row < nrows) v = *(const uint4*)(Acat + (size_t)row * 256 + c8 * 8);
    *(uint4*)(As1 + rn * 264 + c8 * 8) = v;
  }
  __syncthreads();
  v4f acc1[8];
#pragma unroll
  for (int i = 0; i < 8; ++i) acc1[i] = (v4f){0.f, 0.f, 0.f, 0.f};
  for (int kb = 0; kb < 8; ++kb) {
    v8h a = *(const v8h*)((const f16*)As1 + (w * 16 + lid) * 264 + kb * 32 + quad * 8);
#pragma unroll
    for (int ct = 0; ct < 8; ++ct) {
      v8h b = *(const v8h*)((const f16*)Bg1 + (size_t)(ct * 16 + lid) * 256 + kb * 32 + quad * 8);
      acc1[ct] = MFMA16(a, b, acc1[ct]);
    }
  }
  __syncthreads();                 // As1 reads done -> safe to overwrite (As2 aliases)
  // F = leaky(acc1 + b1s + b1u) -> As2 [64][136] f16
#pragma unroll
  for (int ct = 0; ct < 8; ++ct) {
    int col = ct * 16 + lid;
    float bv = b1s[col] + b1u[col];
#pragma unroll
    for (int r = 0; r < 4; ++r) {
      int rn = w * 16 + quad * 4 + r;
      As2[rn * 136 + col] = f2h_bits(leakyf(acc1[ct][r] + bv));
    }
  }
  __syncthreads();
  v4f acc2[16];
#pragma unroll
  for (int i = 0; i < 16; ++i) acc2[i] = (v4f){0.f, 0.f, 0.f, 0.f};
  for (int kb = 0; kb < 4; ++kb) {
    v8h a = *(const v8h*)((const f16*)As2 + (w * 16 + lid) * 136 + kb * 32 + quad * 8);
#pragma unroll
    for (int ct = 0; ct < 16; ++ct) {
      v8h b = *(const v8h*)((const f16*)BW1 + (size_t)(ct * 16 + lid) * 128 + kb * 32 + quad * 8);
      acc2[ct] = MFMA16(a, b, acc2[ct]);
    }
  }
#pragma unroll
  for (int h = 0; h < 2; ++h) {
    __syncthreads();
#pragma unroll
    for (int ct = 0; ct < 8; ++ct) {
      int ctg = h * 8 + ct;
#pragma unroll
      for (int r = 0; r < 4; ++r)
        Es[(w * 16 + quad * 4 + r) * 129 + ct * 16 + lid] = acc2[ctg][r];
    }
    __syncthreads();
    for (int idx = tid; idx < 64 * 128; idx += 256) {
      int rn = idx >> 7, c = idx & 127;
      int row = r0 + rn;
      if (row < nrows)
        G12[(size_t)row * 256 + h * 128 + c] = f2h_bits(Es[rn * 129 + c]);
    }
  }
}

// ---------------- classifier edge kernel: z[e] = G1[src] + G2[dst] + b1 (+ BN sums) ---------
__global__ __launch_bounds__(256) void edge_cls_kernel(
    const int* __restrict__ esrc, const int* __restrict__ edst,
    const u16* __restrict__ G12,          // [N][256] f16: cols 0..127 = G1, 128..255 = G2
    const float* __restrict__ b1,
    u16* __restrict__ zh, float* __restrict__ bnsums, int ne)
{
  __shared__ float redS[512];
  __shared__ float redQ[512];
  const int tid = threadIdx.x;
  const int w = tid >> 6;
  const int lane = tid & 63;
  const uint* Gu = (const uint*)G12;      // row stride 128 uints
  float2 bsv = ((const float2*)b1)[lane];
  float s0 = 0.f, s1 = 0.f, q0 = 0.f, q1 = 0.f;
  const int e0 = blockIdx.x * 64 + w * 16;
#pragma unroll
  for (int k = 0; k < 16; ++k) {
    int e = e0 + k;
    if (e < ne) {
      int sv = esrc[e], dv = edst[e];
      uint a = Gu[(size_t)sv * 128 + lane];
      uint b = Gu[(size_t)dv * 128 + 64 + lane];
      float z0 = h2f((u16)a) + h2f((u16)b) + bsv.x;
      float z1 = h2f((u16)(a >> 16)) + h2f((u16)(b >> 16)) + bsv.y;
      ((uint*)zh)[(size_t)e * 64 + lane] = pack2h(z0, z1);
      s0 += z0; s1 += z1; q0 += z0 * z0; q1 += z1 * z1;
    }
  }
  redS[w * 128 + lane * 2 + 0] = s0;
  redS[w * 128 + lane * 2 + 1] = s1;
  redQ[w * 128 + lane * 2 + 0] = q0;
  redQ[w * 128 + lane * 2 + 1] = q1;
  __syncthreads();
  if (tid < 128) {
    float s = redS[tid] + redS[128 + tid] + redS[256 + tid] + redS[384 + tid];
    float q = redQ[tid] + redQ[128 + tid] + redQ[256 + tid] + redQ[384 + tid];
    float* bnp = bnsums + (size_t)(blockIdx.x & (BNREP - 1)) * 256;
    atomicAdd(&bnp[tid], s);
    atomicAdd(&bnp[128 + tid], q);
  }
}

// ---------------- layer0: fused dual gather + merge -> h1 (fp16), 8-deep MLP ---------------
// r12: unroll 4 -> 8. Avg degree 16 -> sequential L2/L3 round-trips per relation drop 4 -> 2.
__global__ __launch_bounds__(256) void gather_merge0_kernel(
    const u16* __restrict__ colS, const int* __restrict__ cntS, const u16* __restrict__ Ps,
    const u16* __restrict__ colU, const int* __restrict__ cntU, const u16* __restrict__ Pu,
    const float* __restrict__ rsS, const float* __restrict__ rsU,
    const float* __restrict__ bS, const float* __restrict__ bU,
    u16* __restrict__ outh, int nnodes)
{
  int wave = threadIdx.x >> 6;
  int lane = threadIdx.x & 63;
  int node = __builtin_amdgcn_readfirstlane(blockIdx.x * 4 + wave);
  if (node >= nnodes) return;
  const uint* PS2 = (const uint*)Ps;
  const uint* PU2 = (const uint*)Pu;
  float2 aS = make_float2(0.f, 0.f), aU = make_float2(0.f, 0.f);
  {
    const u16* col = colS + (size_t)node * DSTRIDE;
    int cnt = min(cntS[node], DSTRIDE);
    int e = 0;
    for (; e + 8 <= cnt; e += 8) {
      uint v[8];
#pragma unroll
      for (int k = 0; k < 8; ++k) v[k] = PS2[(size_t)col[e + k] * 64 + lane];
#pragma unroll
      for (int k = 0; k < 8; ++k) { aS.x += h2f((u16)v[k]); aS.y += h2f((u16)(v[k] >> 16)); }
    }
    for (; e < cnt; ++e) {
      uint v = PS2[(size_t)col[e] * 64 + lane];
      aS.x += h2f((u16)v); aS.y += h2f((u16)(v >> 16));
    }
  }
  {
    const u16* col = colU + (size_t)node * DSTRIDE;
    int cnt = min(cntU[node], DSTRIDE);
    int e = 0;
    for (; e + 8 <= cnt; e += 8) {
      uint v[8];
#pragma unroll
      for (int k = 0; k < 8; ++k) v[k] = PU2[(size_t)col[e + k] * 64 + lane];
#pragma unroll
      for (int k = 0; k < 8; ++k) { aU.x += h2f((u16)v[k]); aU.y += h2f((u16)(v[k] >> 16)); }
    }
    for (; e < cnt; ++e) {
      uint v = PU2[(size_t)col[e] * 64 + lane];
      aU.x += h2f((u16)v); aU.y += h2f((u16)(v >> 16));
    }
  }
  float rS = rsS[node], rU = rsU[node];
  float2 bsv = ((const float2*)bS)[lane];
  float2 buv = ((const float2*)bU)[lane];
  float o0 = leakyf(aS.x * rS + bsv.x + aU.x * rU + buv.x);
  float o1 = leakyf(aS.y * rS + bsv.y + aU.y * rU + buv.y);
  ((uint*)outh)[(size_t)node * 64 + lane] = pack2h(o0, o1);
}

// ---------------- layer1: fused dual gather -> A_cat fp16 [N][256], 8-deep MLP -------------
// r12: unroll 2 -> 8 (was the worst MLP in the pipeline: 8 sequential round-trips/relation).
__global__ __launch_bounds__(256) void gather_cat1_kernel(
    const u16* __restrict__ colS, const int* __restrict__ cntS,
    const u16* __restrict__ colU, const int* __restrict__ cntU,
    const u16* __restrict__ Fh,
    const float* __restrict__ rsoutS, const float* __restrict__ rsoutU,
    const float* __restrict__ rsinS, const float* __restrict__ rsinU,
    u16* __restrict__ Acat, int nnodes)
{
  int wave = threadIdx.x >> 6;
  int lane = threadIdx.x & 63;
  int node = __builtin_amdgcn_readfirstlane(blockIdx.x * 4 + wave);
  if (node >= nnodes) return;
  const uint* F2 = (const uint*)Fh;
  float2 aS = make_float2(0.f, 0.f), aU = make_float2(0.f, 0.f);
  {
    const u16* col = colS + (size_t)node * DSTRIDE;
    int cnt = min(cntS[node], DSTRIDE);
    int e = 0;
    for (; e + 8 <= cnt; e += 8) {
      int s[8]; float c[8]; uint v[8];
#pragma unroll
      for (int k = 0; k < 8; ++k) s[k] = col[e + k];
#pragma unroll
      for (int k = 0; k < 8; ++k) { c[k] = rsoutS[s[k]]; v[k] = F2[(size_t)s[k] * 64 + lane]; }
#pragma unroll
      for (int k = 0; k < 8; ++k) {
        aS.x += c[k] * h2f((u16)v[k]);
        aS.y += c[k] * h2f((u16)(v[k] >> 16));
      }
    }
    for (; e < cnt; ++e) {
      int s = col[e]; float c = rsoutS[s];
      uint v = F2[(size_t)s * 64 + lane];
      aS.x += c * h2f((u16)v); aS.y += c * h2f((u16)(v >> 16));
    }
  }
  {
    const u16* col = colU + (size_t)node * DSTRIDE;
    int cnt = min(cntU[node], DSTRIDE);
    int e = 0;
    for (; e + 8 <= cnt; e += 8) {
      int s[8]; float c[8]; uint v[8];
#pragma unroll
      for (int k = 0; k < 8; ++k) s[k] = col[e + k];
#pragma unroll
      for (int k = 0; k < 8; ++k) { c[k] = rsoutU[s[k]]; v[k] = F2[(size_t)s[k] * 64 + lane]; }
#pragma unroll
      for (int k = 0; k < 8; ++k) {
        aU.x += c[k] * h2f((u16)v[k]);
        aU.y += c[k] * h2f((u16)(v[k] >> 16));
      }
    }
    for (; e < cnt; ++e) {
      int s = col[e]; float c = rsoutU[s];
      uint v = F2[(size_t)s * 64 + lane];
      aU.x += c * h2f((u16)v); aU.y += c * h2f((u16)(v >> 16));
    }
  }
  float rs = rsinS[node], ru = rsinU[node];
  ((uint*)Acat)[(size_t)node * 128 + lane] = pack2h(aS.x * rs, aS.y * rs);
  ((uint*)Acat)[(size_t)node * 128 + 64 + lane] = pack2h(aU.x * ru, aU.y * ru);
}

// ---------------- output: BN(z) -> relu -> @W2 + b2 (BN coeffs from 64 bnsums replicas) -----
__global__ __launch_bounds__(256) void out_kernel(
    const u16* __restrict__ zh, const float* __restrict__ bnsums,
    const float* __restrict__ g, const float* __restrict__ bb, float M,
    const float* __restrict__ W2, const float* __restrict__ b2,
    void* __restrict__ out, int Mi, const int* __restrict__ flag)
{
  __shared__ float lds[128 * 65];
  __shared__ float red[64 * 8];
  __shared__ float ssL[256];
  const int tid = threadIdx.x;
  const int n = tid & 63;
  const int q = __builtin_amdgcn_readfirstlane(tid >> 6);
  const int r0 = blockIdx.x * 64;
  if (tid < 128) {
    float s = 0.f, s2 = 0.f;
#pragma unroll 8
    for (int r = 0; r < BNREP; ++r) {
      s  += bnsums[r * 256 + tid];
      s2 += bnsums[r * 256 + 128 + tid];
    }
    float mean = s / M;
    float var = s2 / M - mean * mean;
    float sc = g[tid] * __builtin_amdgcn_rsqf(var + 1e-5f);
    ssL[tid] = sc;
    ssL[128 + tid] = bb[tid] - mean * sc;
  }
  // r12: uint loads (2 cols/load) instead of scalar u16
  for (int idx = tid; idx < 64 * 64; idx += 256) {
    int rn = idx >> 6, j2 = idx & 63;
    int row = r0 + rn;
    uint v = (row < Mi) ? ((const uint*)zh)[(size_t)row * 64 + j2] : 0u;
    lds[(2 * j2) * 65 + rn] = h2f((u16)v);
    lds[(2 * j2 + 1) * 65 + rn] = h2f((u16)(v >> 16));
  }
  __syncthreads();
  float a0 = 0.f, a1 = 0.f;
#pragma unroll 8
  for (int jj = 0; jj < 32; ++jj) {
    int j = q * 32 + jj;
    float y = lds[j * 65 + n] * ssL[j] + ssL[128 + j];
    y = y > 0.f ? y : 0.f;
    a0 += y * W2[j];
    a1 += y * W2[128 + j];
  }
  red[n * 8 + q * 2 + 0] = a0;
  red[n * 8 + q * 2 + 1] = a1;
  __syncthreads();
  if (q == 0 && (r0 + n) < Mi) {
    float o0 = red[n * 8] + red[n * 8 + 2] + red[n * 8 + 4] + red[n * 8 + 6] + b2[0];
    float o1 = red[n * 8 + 1] + red[n * 8 + 3] + red[n * 8 + 5] + red[n * 8 + 7] + b2[1];
    size_t oi = (size_t)(r0 + n) * 2;
    if (*flag) {
      ((bf16*)out)[oi + 0] = __float2bfloat16(o0);
      ((bf16*)out)[oi + 1] = __float2bfloat16(o1);
    } else {
      ((float*)out)[oi + 0] = o0;
      ((float*)out)[oi + 1] = o1;
    }
  }
}

// ==================================================================================
extern "C" void kernel_launch(void* const* d_in, const int* in_sizes, int n_in,
                              void* d_out, int out_size, void* d_ws, size_t ws_size,
                              hipStream_t stream) {
  (void)in_sizes; (void)n_in; (void)out_size; (void)ws_size;
  const int N = N_NODES;
  const int* inputs_s  = (const int*)d_in[0];
  const int* inputs_sm = (const int*)d_in[1];
  const int* inputs_c  = (const int*)d_in[2];
  const int* inputs_co = (const int*)d_in[3];
  const int* inputs_sl = (const int*)d_in[4];
  const int* sim_src   = (const int*)d_in[5];
  const int* sim_dst   = (const int*)d_in[6];
  const int* user_src  = (const int*)d_in[7];
  const int* user_dst  = (const int*)d_in[8];
  const int* esub_src  = (const int*)d_in[9];
  const int* esub_dst  = (const int*)d_in[10];

  // ---- workspace layout ----
  char* base = (char*)d_ws;
  size_t off = 0;
  auto alloc = [&](size_t bytes) -> char* {
    char* p = base + off;
    off += (bytes + 255) & ~(size_t)255;
    return p;
  };
  int* dflag    = (int*)alloc(256);
  f16* Whh_h    = (f16*)alloc(2 * 256 * 64 * 2);
  float* Xperm  = (float*)alloc(2 * 128 * 256 * 4);
  u16* Bfc      = (u16*)alloc(64 * 128 * 2);
  u16* BW1      = (u16*)alloc(256 * 128 * 2);
  u16* Bg0      = (u16*)alloc(256 * 256 * 2);
  u16* Bg1      = (u16*)alloc(128 * 256 * 2);
  u16* P_embc_h = (u16*)alloc(6464 * 2);
  u16* P_embco_h= (u16*)alloc(5888 * 2);
  u16* P_embs_h = (u16*)alloc(384 * 2);
  float* P_fcb  = (float*)alloc(64 * 4);
  float* P_b1   = (float*)alloc(128 * 4);
  float* P_g0sb = (float*)alloc(128 * 4);
  float* P_g0ub = (float*)alloc(128 * 4);
  float* P_g1sb = (float*)alloc(128 * 4);
  float* P_g1ub = (float*)alloc(128 * 4);
  float* P_bng  = (float*)alloc(128 * 4);
  float* P_bnb  = (float*)alloc(128 * 4);
  float* P_W2   = (float*)alloc(256 * 4);
  float* P_b2   = (float*)alloc(2 * 4);
  int* lens     = (int*)alloc((size_t)N * 4);
  int* perm     = (int*)alloc((size_t)N * 4);
  float* rsq4   = (float*)alloc((size_t)4 * N * 4);
  // ---- contiguous zero region (ONE memset): cnt4 | cnt33 | cur33 | gcur | bnsums[64] ----
  char* zbase   = alloc((size_t)4 * N * 4 + 4096 + BNREP * 256 * 4);
  int* cnt4     = (int*)zbase;                                    // [outS | inS | outU | inU]
  int* cnt33    = (int*)(zbase + (size_t)4 * N * 4);
  int* cur33    = cnt33 + 64;
  int* gcur     = (int*)(zbase + (size_t)4 * N * 4 + 512);        // 2*NBUCK ints (3128B)
  float* bnsums = (float*)(zbase + (size_t)4 * N * 4 + 4096);     // 64 replicas x 256 floats
  const size_t zbytes = (size_t)4 * N * 4 + 4096 + BNREP * 256 * 4;
  char* bufA = alloc((size_t)N * 256 * 4);
  char* bufB = alloc((size_t)N * 256 * 2);   // hcat_h [N][128]; later h1_h [N][128]
  char* bufC = alloc((size_t)N * 256 * 2);
  u16* zh      = (u16*)bufA;
  u16* col_sim = (u16*)(bufA + (size_t)N * 256 * 2);
  u16* col_usr = (u16*)(bufA + (size_t)N * 256 * 2 + (size_t)N * DSTRIDE * 2);
  u16* hcat_h = (u16*)bufB;
  u16* h1_h   = (u16*)bufB;
  u32* bucket = (u32*)bufC;                  // 2*NBUCK*BCAP*4 = 9.6MB <= 25.6MB
  u16* Ps_h   = (u16*)bufC;
  u16* Pu_h   = Ps_h + (size_t)N * 128;
  u16* Acat   = (u16*)bufC;
  u16* G12    = (u16*)bufC;                  // [N][256] f16 = 25.6MB (in-place over Acat)

  const int NB64 = (N + 63) / 64;              // 782
  const int NBZ  = (NE_SUB + 63) / 64;         // 3125

  // ---- 0. single memset for all accumulated regions ----
  hipMemsetAsync(zbase, 0, zbytes, stream);

  // ---- 1. merged prep + phase-1 edge binning ----
  PrepArgs PA;
  PA.Whh_f = d_in[16]; PA.Whh_b = d_in[19]; PA.fc_W = d_in[21]; PA.cls_W1 = d_in[31];
  PA.g0sW = d_in[23]; PA.g0uW = d_in[25]; PA.g1sW = d_in[27]; PA.g1uW = d_in[29];
  PA.emb_cat = d_in[12]; PA.emb_country = d_in[13]; PA.emb_sl = d_in[14];
  PA.fc_b = d_in[22]; PA.cls_b1 = d_in[32]; PA.g0sb = d_in[24]; PA.g0ub = d_in[26];
  PA.g1sb = d_in[28]; PA.g1ub = d_in[30]; PA.bn_g = d_in[33]; PA.bn_b = d_in[34];
  PA.cls_W2 = d_in[35]; PA.cls_b2 = d_in[36];
  PA.emb_url = d_in[11]; PA.Wih_f = d_in[15]; PA.b_f = d_in[17]; PA.Wih_b = d_in[18]; PA.b_b = d_in[20];
  PA.Whh_h = Whh_h; PA.Bfc = Bfc; PA.BW1 = BW1; PA.Bg0 = Bg0; PA.Bg1 = Bg1;
  PA.embc_h = P_embc_h; PA.embco_h = P_embco_h; PA.embs_h = P_embs_h;
  PA.fcb = P_fcb; PA.b1 = P_b1; PA.g0sbP = P_g0sb; PA.g0ubP = P_g0ub; PA.g1sbP = P_g1sb; PA.g1ubP = P_g1ub;
  PA.bngP = P_bng; PA.bnbP = P_bnb; PA.W2P = P_W2; PA.b2P = P_b2;
  PA.dflag = dflag; PA.Xperm = Xperm;
  PA.sm = inputs_sm; PA.lens = lens; PA.cnt33 = cnt33;
  PA.s0 = sim_src; PA.d0 = sim_dst; PA.s1 = user_src; PA.d1 = user_dst;
  PA.cnt4 = cnt4; PA.gcur = gcur; PA.bucket = bucket;
  prep_graph_kernel<<<PG_BLOCKS, 256, 0, stream>>>(PA);

  // ---- 2. permfill (perm needed by LSTM) ----
  permfill_kernel<<<PF_BLOCKS, 256, 0, stream>>>(lens, cnt33, cur33, perm);

  // ---- 3. LSTM -> hcat_h; extra blocks run phase-2 scatter + rsq (hidden under LSTM) ----
  lstm_mfma_kernel<<<dim3(LSTM_XB + LSTM_EXTRA, 2), 256, 0, stream>>>(
      perm, lens, inputs_s, Xperm, Whh_h, hcat_h,
      bucket, gcur, col_sim, col_usr, cnt4, rsq4, N);

  // ---- 4+5 fused: hcat -> [h_url|emb] (LDS) -> layer0 dual projection -> Ps, Pu ----
  fuse45_kernel<<<NB64, 256, 0, stream>>>(
      hcat_h, Bfc, P_fcb, inputs_c, inputs_co, inputs_sl,
      P_embc_h, P_embco_h, P_embs_h, Bg0, rsq4, rsq4 + 2 * N, Ps_h, Pu_h, N);

  // ---- 6. layer0 gather+merge -> h1 ----
  gather_merge0_kernel<<<(N + 3) / 4, 256, 0, stream>>>(col_sim, cnt4 + N, Ps_h,
                                                        col_usr, cnt4 + 3 * N, Pu_h,
                                                        rsq4 + N, rsq4 + 3 * N, P_g0sb, P_g0ub, h1_h, N);

  // ---- 7. layer1 dual gather (scaled) -> Acat ----
  gather_cat1_kernel<<<(N + 3) / 4, 256, 0, stream>>>(col_sim, cnt4 + N, col_usr, cnt4 + 3 * N, h1_h,
                                                      rsq4, rsq4 + 2 * N, rsq4 + N, rsq4 + 3 * N, Acat, N);

  // ---- 8+9a fused: Acat -> F (LDS) -> G12 (in place over Acat) ----
  fuse89_kernel<<<NB64, 256, 0, stream>>>(Acat, Bg1, P_g1sb, P_g1ub, BW1, G12, N);

  // ---- 9b. z[e] = G1[src] + G2[dst] + b1 -> zh (+ BN partial sums, 64-way replicated) ----
  edge_cls_kernel<<<NBZ, 256, 0, stream>>>(esub_src, esub_dst, G12, P_b1, zh, bnsums, NE_SUB);

  // ---- 10. BN + relu + W2 (folds the 64 replicas) ----
  out_kernel<<<NBZ, 256, 0, stream>>>(zh, bnsums, P_bng, P_bnb, (float)NE_SUB,
                                      P_W2, P_b2, d_out, NE_SUB, dflag);
}